// Round 1
// baseline (463.972 us; speedup 1.0000x reference)
//
#include <hip/hip_runtime.h>
#include <stdint.h>

// Problem constants
#define BB 4
#define TT 1024
#define DIM 2048
#define NH 16
#define HD 128
#define MR 4096   // BB*TT rows

typedef __attribute__((ext_vector_type(4))) float    f32x4;
typedef __attribute__((ext_vector_type(8))) uint16_t u16x8;
typedef __attribute__((ext_vector_type(4))) uint16_t u16x4;
typedef __attribute__((ext_vector_type(8))) __bf16   bf16x8;

static __device__ __forceinline__ uint16_t f2bf(float f) {
  uint32_t u = __builtin_bit_cast(uint32_t, f);
  u += 0x7fffu + ((u >> 16) & 1u);   // round-to-nearest-even
  return (uint16_t)(u >> 16);
}
static __device__ __forceinline__ float bf2f(uint16_t b) {
  uint32_t u = ((uint32_t)b) << 16;
  return __builtin_bit_cast(float, u);
}

static __device__ __forceinline__ f32x4 mfma16(u16x8 a, u16x8 b, f32x4 c) {
  return __builtin_amdgcn_mfma_f32_16x16x32_bf16(
      __builtin_bit_cast(bf16x8, a), __builtin_bit_cast(bf16x8, b), c, 0, 0, 0);
}

// async global->LDS, 16B per lane; LDS dest must be linear in lane order
static __device__ __forceinline__ void load_lds_16B(const void* g, void* l) {
  __builtin_amdgcn_global_load_lds(
      (const __attribute__((address_space(1))) void*)g,
      (__attribute__((address_space(3))) void*)l, 16, 0, 0);
}

// ---------------- cast fp32 -> bf16 (vectorized) ----------------
__global__ __launch_bounds__(256) void cast_f32_bf16(const float* __restrict__ in,
                                                     uint16_t* __restrict__ out, int n4) {
  int i = blockIdx.x * 256 + threadIdx.x;
  if (i >= n4) return;
  f32x4 v = ((const f32x4*)in)[i];
  u16x4 o;
  o[0] = f2bf(v[0]); o[1] = f2bf(v[1]); o[2] = f2bf(v[2]); o[3] = f2bf(v[3]);
  ((u16x4*)out)[i] = o;
}

// ---------------- GEMM: C[M,N] = A[M,K] * Bt[N,K]^T (both row-major bf16) ----
// 128x128 tile, BK=64, 256 threads = 4 waves (2x2), each wave 64x64 = 4x4 MFMA frags.
template <int OUTF32>
__global__ __launch_bounds__(256) void gemm_bt(const uint16_t* __restrict__ A,
                                               const uint16_t* __restrict__ Bt,
                                               float* __restrict__ Cf,
                                               uint16_t* __restrict__ Cb,
                                               int M, int N, int K) {
  __shared__ __attribute__((aligned(16))) uint16_t As[128][64];
  __shared__ __attribute__((aligned(16))) uint16_t Bs[128][64];
  const int tid  = threadIdx.x;
  const int lane = tid & 63;
  const int wave = tid >> 6;
  const int wr   = (wave >> 1) * 64;
  const int wc   = (wave & 1) * 64;
  const int lrow = lane & 15;
  const int lgrp = lane >> 4;
  const long bRow = (long)blockIdx.y * 128;
  const long bCol = (long)blockIdx.x * 128;

  const f32x4 fz = {0.f, 0.f, 0.f, 0.f};
  f32x4 acc[4][4];
#pragma unroll
  for (int m = 0; m < 4; ++m)
#pragma unroll
    for (int n = 0; n < 4; ++n) acc[m][n] = fz;

  const int srow = tid >> 3;        // 0..31
  const int scol = (tid & 7) * 8;   // 0..56
  const int nkt = K >> 6;
  for (int kt = 0; kt < nkt; ++kt) {
    const int kb = kt << 6;
    __syncthreads();
#pragma unroll
    for (int i = 0; i < 4; ++i) {
      load_lds_16B(A  + (bRow + srow + i * 32) * (long)K + kb + scol,
                   &As[0][0] + (size_t)(i * 256 + tid) * 8);
      load_lds_16B(Bt + (bCol + srow + i * 32) * (long)K + kb + scol,
                   &Bs[0][0] + (size_t)(i * 256 + tid) * 8);
    }
    __syncthreads();
#pragma unroll
    for (int kk = 0; kk < 2; ++kk) {
      const int ko = kk * 32 + lgrp * 8;
      u16x8 af[4], bf[4];
#pragma unroll
      for (int m = 0; m < 4; ++m) af[m] = *(const u16x8*)&As[wr + m * 16 + lrow][ko];
#pragma unroll
      for (int n = 0; n < 4; ++n) bf[n] = *(const u16x8*)&Bs[wc + n * 16 + lrow][ko];
#pragma unroll
      for (int m = 0; m < 4; ++m)
#pragma unroll
        for (int n = 0; n < 4; ++n) acc[m][n] = mfma16(af[m], bf[n], acc[m][n]);
    }
  }
#pragma unroll
  for (int m = 0; m < 4; ++m)
#pragma unroll
    for (int n = 0; n < 4; ++n) {
      const long grow0 = bRow + wr + m * 16 + lgrp * 4;
      const long gcol  = bCol + wc + n * 16 + lrow;
#pragma unroll
      for (int r = 0; r < 4; ++r) {
        const long idx = (grow0 + r) * (long)N + gcol;
        if (OUTF32) Cf[idx] = acc[m][n][r];
        else        Cb[idx] = f2bf(acc[m][n][r]);
      }
    }
}

// ---------------- RoPE in-place on q and k (bf16), pairwise rotate ----------
__global__ __launch_bounds__(256) void rope_qk(uint16_t* __restrict__ q,
                                               uint16_t* __restrict__ k,
                                               const float* __restrict__ cosT,
                                               const float* __restrict__ sinT) {
  const int p = blockIdx.x * 256 + threadIdx.x;   // [0, MR * DIM/2)
  if (p >= MR * (DIM / 2)) return;
  const int row = p >> 10;          // DIM/2 = 1024 pairs per row
  const int j   = p & 1023;
  const int h   = j >> 6;           // 64 pairs per head
  const int fi  = j & 63;
  const int t   = row & (TT - 1);
  const float c = cosT[t * 64 + fi];
  const float s = sinT[t * 64 + fi];
  const long off = (long)row * DIM + h * HD + fi * 2;

  uint32_t qp = *(uint32_t*)(q + off);
  float qe = bf2f((uint16_t)(qp & 0xffff));
  float qo = bf2f((uint16_t)(qp >> 16));
  *(uint32_t*)(q + off) =
      (uint32_t)f2bf(qe * c - qo * s) | ((uint32_t)f2bf(qe * s + qo * c) << 16);

  uint32_t kp = *(uint32_t*)(k + off);
  float ke = bf2f((uint16_t)(kp & 0xffff));
  float ko = bf2f((uint16_t)(kp >> 16));
  *(uint32_t*)(k + off) =
      (uint32_t)f2bf(ke * c - ko * s) | ((uint32_t)f2bf(ke * s + ko * c) << 16);
}

// ---------------- Flash attention fwd ---------------------------------------
// grid (BB*NH, TT/64). 256 threads = 4 waves; each wave owns 16 q-rows.
// Q in registers; K tile via global_load_lds; V tile transposed in LDS;
// online softmax in fp32; P via LDS round-trip for MFMA A-layout.
__global__ __launch_bounds__(256) void attn_fwd(const uint16_t* __restrict__ Q,
                                                const uint16_t* __restrict__ K,
                                                const uint16_t* __restrict__ V,
                                                uint16_t* __restrict__ O) {
  __shared__ __attribute__((aligned(16))) uint16_t Ks[64][128];    // 16 KB
  __shared__ __attribute__((aligned(16))) uint16_t Vt[128][72];    // 18 KB (V^T, padded)
  __shared__ __attribute__((aligned(16))) uint16_t Ps[4][16][72];  // 9 KB
  const int tid  = threadIdx.x;
  const int lane = tid & 63;
  const int wave = tid >> 6;
  const int lrow = lane & 15;
  const int lgrp = lane >> 4;
  const int b  = blockIdx.x >> 4;
  const int h  = blockIdx.x & 15;
  const int qt = blockIdx.y;
  const long colBase = (long)h * HD;
  const long rs = DIM;
  const long qrow0 = (long)b * TT + qt * 64 + wave * 16;

  u16x8 qf[4];
#pragma unroll
  for (int kkk = 0; kkk < 4; ++kkk)
    qf[kkk] = *(const u16x8*)(Q + (qrow0 + lrow) * rs + colBase + kkk * 32 + lgrp * 8);

  const f32x4 fz = {0.f, 0.f, 0.f, 0.f};
  f32x4 oacc[8];
#pragma unroll
  for (int nf = 0; nf < 8; ++nf) oacc[nf] = fz;
  float mst[4] = {-1e30f, -1e30f, -1e30f, -1e30f};
  float lst[4] = {0.f, 0.f, 0.f, 0.f};
  const float scale = 0.08838834764831845f;  // 1/sqrt(128)

  const int srow = tid >> 4;         // 0..15 (16B chunks: 16 per 128-wide row)
  const int scol = (tid & 15) * 8;   // 0..120

  for (int kt2 = 0; kt2 < TT / 64; ++kt2) {
    const long krow = (long)b * TT + kt2 * 64;
    __syncthreads();   // prev tile fully consumed
#pragma unroll
    for (int i = 0; i < 4; ++i)
      load_lds_16B(K + (krow + srow + i * 16) * rs + colBase + scol,
                   &Ks[0][0] + (size_t)(i * 256 + tid) * 8);
    u16x8 vreg[4];
#pragma unroll
    for (int i = 0; i < 4; ++i)
      vreg[i] = *(const u16x8*)(V + (krow + srow + i * 16) * rs + colBase + scol);
#pragma unroll
    for (int i = 0; i < 4; ++i)
#pragma unroll
      for (int jj = 0; jj < 8; ++jj)
        Vt[scol + jj][srow + i * 16] = (uint16_t)vreg[i][jj];
    __syncthreads();   // K (async) + Vt visible

    // S = Q K^T : 16x64 per wave
    f32x4 sacc[4];
#pragma unroll
    for (int n = 0; n < 4; ++n) sacc[n] = fz;
#pragma unroll
    for (int kkk = 0; kkk < 4; ++kkk) {
      const int ko = kkk * 32 + lgrp * 8;
#pragma unroll
      for (int n = 0; n < 4; ++n) {
        u16x8 bf = *(const u16x8*)&Ks[n * 16 + lrow][ko];
        sacc[n] = mfma16(qf[kkk], bf, sacc[n]);
      }
    }
#pragma unroll
    for (int n = 0; n < 4; ++n) sacc[n] *= scale;

    // row max over 64 cols: 4 frags then 16-lane butterfly
    float rmax[4];
#pragma unroll
    for (int r = 0; r < 4; ++r)
      rmax[r] = fmaxf(fmaxf(sacc[0][r], sacc[1][r]), fmaxf(sacc[2][r], sacc[3][r]));
#pragma unroll
    for (int off = 8; off >= 1; off >>= 1)
#pragma unroll
      for (int r = 0; r < 4; ++r)
        rmax[r] = fmaxf(rmax[r], __shfl_xor(rmax[r], off, 64));

    float alpha[4];
#pragma unroll
    for (int r = 0; r < 4; ++r) {
      float mnew = fmaxf(mst[r], rmax[r]);
      alpha[r] = __expf(mst[r] - mnew);
      mst[r] = mnew;
    }
    float rsum[4] = {0.f, 0.f, 0.f, 0.f};
#pragma unroll
    for (int n = 0; n < 4; ++n)
#pragma unroll
      for (int r = 0; r < 4; ++r) {
        float pv = __expf(sacc[n][r] - mst[r]);
        rsum[r] += pv;
        Ps[wave][lgrp * 4 + r][n * 16 + lrow] = f2bf(pv);
      }
#pragma unroll
    for (int off = 8; off >= 1; off >>= 1)
#pragma unroll
      for (int r = 0; r < 4; ++r) rsum[r] += __shfl_xor(rsum[r], off, 64);
#pragma unroll
    for (int r = 0; r < 4; ++r) lst[r] = lst[r] * alpha[r] + rsum[r];
#pragma unroll
    for (int nf = 0; nf < 8; ++nf)
#pragma unroll
      for (int r = 0; r < 4; ++r) oacc[nf][r] *= alpha[r];

    __syncthreads();   // P writes (cross-lane) visible before A-frag reads

    // O += P V : P is 16x64, V tile 64x128 -> 8 col frags
#pragma unroll
    for (int kk2 = 0; kk2 < 2; ++kk2) {
      u16x8 af = *(const u16x8*)&Ps[wave][lrow][kk2 * 32 + lgrp * 8];
#pragma unroll
      for (int nf = 0; nf < 8; ++nf) {
        u16x8 bf = *(const u16x8*)&Vt[nf * 16 + lrow][kk2 * 32 + lgrp * 8];
        oacc[nf] = mfma16(af, bf, oacc[nf]);
      }
    }
  }

  float inv[4];
#pragma unroll
  for (int r = 0; r < 4; ++r) inv[r] = 1.0f / lst[r];
#pragma unroll
  for (int nf = 0; nf < 8; ++nf)
#pragma unroll
    for (int r = 0; r < 4; ++r)
      O[(qrow0 + lgrp * 4 + r) * rs + colBase + nf * 16 + lrow] =
          f2bf(oacc[nf][r] * inv[r]);
}

// ---------------- launch ----------------------------------------------------
extern "C" void kernel_launch(void* const* d_in, const int* in_sizes, int n_in,
                              void* d_out, int out_size, void* d_ws, size_t ws_size,
                              hipStream_t stream) {
  const float* x  = (const float*)d_in[0];
  const float* fc = (const float*)d_in[1];
  const float* fs = (const float*)d_in[2];
  const float* wq = (const float*)d_in[3];
  const float* wk = (const float*)d_in[4];
  const float* wv = (const float*)d_in[5];
  const float* wo = (const float*)d_in[6];
  float* out = (float*)d_out;

  // ws layout (bf16 elements). Needs 58,720,256 * 2B = 112 MiB of d_ws.
  uint16_t* w16 = (uint16_t*)d_ws;
  uint16_t* xb  = w16;                  // 8,388,608
  uint16_t* wqb = xb  + 8388608;        // 4,194,304
  uint16_t* wkb = wqb + 4194304;
  uint16_t* wvb = wkb + 4194304;
  uint16_t* wob = wvb + 4194304;
  uint16_t* qb  = wob + 4194304;        // 8,388,608 each
  uint16_t* kb  = qb  + 8388608;
  uint16_t* vb  = kb  + 8388608;
  uint16_t* ob  = vb  + 8388608;

  // casts
  cast_f32_bf16<<<8192, 256, 0, stream>>>(x,  xb,  8388608 / 4);
  cast_f32_bf16<<<4096, 256, 0, stream>>>(wq, wqb, 4194304 / 4);
  cast_f32_bf16<<<4096, 256, 0, stream>>>(wk, wkb, 4194304 / 4);
  cast_f32_bf16<<<4096, 256, 0, stream>>>(wv, wvb, 4194304 / 4);
  cast_f32_bf16<<<4096, 256, 0, stream>>>(wo, wob, 4194304 / 4);

  // QKV projections: (4096x2048) = xb @ w^T
  dim3 gp(DIM / 128, MR / 128);
  gemm_bt<0><<<gp, 256, 0, stream>>>(xb, wqb, nullptr, qb, MR, DIM, DIM);
  gemm_bt<0><<<gp, 256, 0, stream>>>(xb, wkb, nullptr, kb, MR, DIM, DIM);
  gemm_bt<0><<<gp, 256, 0, stream>>>(xb, wvb, nullptr, vb, MR, DIM, DIM);

  // RoPE on q,k
  rope_qk<<<(MR * (DIM / 2)) / 256, 256, 0, stream>>>(qb, kb, fc, fs);

  // attention
  dim3 ga(BB * NH, TT / 64);
  attn_fwd<<<ga, 256, 0, stream>>>(qb, kb, vb, ob);

  // output projection -> fp32 d_out
  gemm_bt<1><<<gp, 256, 0, stream>>>(ob, wob, out, nullptr, MR, DIM, DIM);
}

// Round 3
// 325.856 us; speedup vs baseline: 1.4239x; 1.4239x over previous
//
#include <hip/hip_runtime.h>
#include <stdint.h>

// Problem constants
#define BB 4
#define TT 1024
#define DIM 2048
#define NH 16
#define HD 128
#define MR 4096   // BB*TT rows

typedef __attribute__((ext_vector_type(4))) float    f32x4;
typedef __attribute__((ext_vector_type(8))) uint16_t u16x8;
typedef __attribute__((ext_vector_type(4))) uint16_t u16x4;
typedef __attribute__((ext_vector_type(4))) short    s16x4;
typedef __attribute__((ext_vector_type(8))) __bf16   bf16x8;

static __device__ __forceinline__ uint16_t f2bf(float f) {
  uint32_t u = __builtin_bit_cast(uint32_t, f);
  u += 0x7fffu + ((u >> 16) & 1u);   // round-to-nearest-even
  return (uint16_t)(u >> 16);
}
static __device__ __forceinline__ float bf2f(uint16_t b) {
  uint32_t u = ((uint32_t)b) << 16;
  return __builtin_bit_cast(float, u);
}

static __device__ __forceinline__ f32x4 mfma16(u16x8 a, u16x8 b, f32x4 c) {
  return __builtin_amdgcn_mfma_f32_16x16x32_bf16(
      __builtin_bit_cast(bf16x8, a), __builtin_bit_cast(bf16x8, b), c, 0, 0, 0);
}

// async global->LDS, 16B per lane; LDS dest must be linear in lane order
static __device__ __forceinline__ void load_lds_16B(const void* g, void* l) {
  __builtin_amdgcn_global_load_lds(
      (const __attribute__((address_space(1))) void*)g,
      (__attribute__((address_space(3))) void*)l, 16, 0, 0);
}

// paired hardware transpose reads at byteoff and byteoff+128.
// Semantics (m156/m162): each lane fetches 8B at ITS OWN address; the 16-lane
// group's 128B (in lane order) forms a 4x16 bf16 row-major tile; lane l
// receives column (l&15). Caller passes per-lane addr = subtile_base+(l&15)*8.
static __device__ __forceinline__ void trpair(const uint16_t* base, int byteoff,
                                              u16x4& lo, u16x4& hi) {
  __attribute__((address_space(3))) char* ap =
      (__attribute__((address_space(3))) char*)(void*)base + byteoff;
#if defined(__has_builtin) && __has_builtin(__builtin_amdgcn_ds_read_tr16_b64_v4i16)
  s16x4 r0 = __builtin_amdgcn_ds_read_tr16_b64_v4i16(
      (__attribute__((address_space(3))) s16x4*)ap);
  s16x4 r1 = __builtin_amdgcn_ds_read_tr16_b64_v4i16(
      (__attribute__((address_space(3))) s16x4*)(ap + 128));
  lo = __builtin_bit_cast(u16x4, r0);
  hi = __builtin_bit_cast(u16x4, r1);
#else
  uint32_t a32 = (uint32_t)(uintptr_t)ap;
  asm volatile("ds_read_b64_tr_b16 %0, %2\n\t"
               "ds_read_b64_tr_b16 %1, %2 offset:128\n\t"
               "s_waitcnt lgkmcnt(0)"
               : "=&v"(lo), "=&v"(hi) : "v"(a32));
#endif
}

// ---------------- cast fp32 -> bf16 (vectorized) ----------------
__global__ __launch_bounds__(256) void cast_f32_bf16(const float* __restrict__ in,
                                                     uint16_t* __restrict__ out, int n4) {
  int i = blockIdx.x * 256 + threadIdx.x;
  if (i >= n4) return;
  f32x4 v = ((const f32x4*)in)[i];
  u16x4 o;
  o[0] = f2bf(v[0]); o[1] = f2bf(v[1]); o[2] = f2bf(v[2]); o[3] = f2bf(v[3]);
  ((u16x4*)out)[i] = o;
}

// ---------------- GEMM: C[M,N] = A[M,K] * Bt[N,K]^T (both row-major bf16) ----
// 128x128 tile, BK=64, 256 threads = 4 waves (2x2), each wave 64x64 = 4x4 MFMA frags.
template <int OUTF32>
__global__ __launch_bounds__(256) void gemm_bt(const uint16_t* __restrict__ A,
                                               const uint16_t* __restrict__ Bt,
                                               float* __restrict__ Cf,
                                               uint16_t* __restrict__ Cb,
                                               int M, int N, int K) {
  __shared__ __attribute__((aligned(16))) uint16_t As[128][64];
  __shared__ __attribute__((aligned(16))) uint16_t Bs[128][64];
  const int tid  = threadIdx.x;
  const int lane = tid & 63;
  const int wave = tid >> 6;
  const int wr   = (wave >> 1) * 64;
  const int wc   = (wave & 1) * 64;
  const int lrow = lane & 15;
  const int lgrp = lane >> 4;
  const long bRow = (long)blockIdx.y * 128;
  const long bCol = (long)blockIdx.x * 128;

  const f32x4 fz = {0.f, 0.f, 0.f, 0.f};
  f32x4 acc[4][4];
#pragma unroll
  for (int m = 0; m < 4; ++m)
#pragma unroll
    for (int n = 0; n < 4; ++n) acc[m][n] = fz;

  const int srow = tid >> 3;        // 0..31
  const int scol = (tid & 7) * 8;   // 0..56
  const int nkt = K >> 6;
  for (int kt = 0; kt < nkt; ++kt) {
    const int kb = kt << 6;
    __syncthreads();
#pragma unroll
    for (int i = 0; i < 4; ++i) {
      load_lds_16B(A  + (bRow + srow + i * 32) * (long)K + kb + scol,
                   &As[0][0] + (size_t)(i * 256 + tid) * 8);
      load_lds_16B(Bt + (bCol + srow + i * 32) * (long)K + kb + scol,
                   &Bs[0][0] + (size_t)(i * 256 + tid) * 8);
    }
    __syncthreads();
#pragma unroll
    for (int kk = 0; kk < 2; ++kk) {
      const int ko = kk * 32 + lgrp * 8;
      u16x8 af[4], bf[4];
#pragma unroll
      for (int m = 0; m < 4; ++m) af[m] = *(const u16x8*)&As[wr + m * 16 + lrow][ko];
#pragma unroll
      for (int n = 0; n < 4; ++n) bf[n] = *(const u16x8*)&Bs[wc + n * 16 + lrow][ko];
#pragma unroll
      for (int m = 0; m < 4; ++m)
#pragma unroll
        for (int n = 0; n < 4; ++n) acc[m][n] = mfma16(af[m], bf[n], acc[m][n]);
    }
  }
#pragma unroll
  for (int m = 0; m < 4; ++m)
#pragma unroll
    for (int n = 0; n < 4; ++n) {
      const long grow0 = bRow + wr + m * 16 + lgrp * 4;
      const long gcol  = bCol + wc + n * 16 + lrow;
#pragma unroll
      for (int r = 0; r < 4; ++r) {
        const long idx = (grow0 + r) * (long)N + gcol;
        if (OUTF32) Cf[idx] = acc[m][n][r];
        else        Cb[idx] = f2bf(acc[m][n][r]);
      }
    }
}

// ---------------- RoPE in-place on q and k (bf16), pairwise rotate ----------
__global__ __launch_bounds__(256) void rope_qk(uint16_t* __restrict__ q,
                                               uint16_t* __restrict__ k,
                                               const float* __restrict__ cosT,
                                               const float* __restrict__ sinT) {
  const int p = blockIdx.x * 256 + threadIdx.x;   // [0, MR * DIM/2)
  if (p >= MR * (DIM / 2)) return;
  const int row = p >> 10;          // DIM/2 = 1024 pairs per row
  const int j   = p & 1023;
  const int h   = j >> 6;           // 64 pairs per head
  const int fi  = j & 63;
  const int t   = row & (TT - 1);
  const float c = cosT[t * 64 + fi];
  const float s = sinT[t * 64 + fi];
  const long off = (long)row * DIM + h * HD + fi * 2;

  uint32_t qp = *(uint32_t*)(q + off);
  float qe = bf2f((uint16_t)(qp & 0xffff));
  float qo = bf2f((uint16_t)(qp >> 16));
  *(uint32_t*)(q + off) =
      (uint32_t)f2bf(qe * c - qo * s) | ((uint32_t)f2bf(qe * s + qo * c) << 16);

  uint32_t kp = *(uint32_t*)(k + off);
  float ke = bf2f((uint16_t)(kp & 0xffff));
  float ko = bf2f((uint16_t)(kp >> 16));
  *(uint32_t*)(k + off) =
      (uint32_t)f2bf(ke * c - ko * s) | ((uint32_t)f2bf(ke * s + ko * c) << 16);
}

// ---------------- Flash attention fwd ---------------------------------------
// grid (BB*NH, TT/64). 256 threads = 4 waves; each wave owns 16 q-rows.
// Q in registers; K tile via global_load_lds with XOR-swizzled source
// (linear dest, swizzled read -> conflict-free); V tile via global_load_lds
// into [d16][kv/4][4][16] subtiles consumed with ds_read_b64_tr_b16
// (per-lane addr = subtile_base + (lane&15)*8B);
// online softmax in fp32; P via per-wave LDS round-trip for MFMA A-layout.
__global__ __launch_bounds__(256) void attn_fwd(const uint16_t* __restrict__ Q,
                                                const uint16_t* __restrict__ K,
                                                const uint16_t* __restrict__ V,
                                                uint16_t* __restrict__ O) {
  __shared__ __attribute__((aligned(16))) uint16_t Ks[64 * 128];   // 16 KB swizzled
  __shared__ __attribute__((aligned(16))) uint16_t Vs[64 * 128];   // 16 KB subtiled
  __shared__ __attribute__((aligned(16))) uint16_t Ps[4][16][72];  // 9 KB
  const int tid  = threadIdx.x;
  const int lane = tid & 63;
  const int wave = tid >> 6;
  const int lrow = lane & 15;
  const int lgrp = lane >> 4;
  const int b  = blockIdx.x >> 4;
  const int h  = blockIdx.x & 15;
  const int qt = blockIdx.y;
  const long colBase = (long)h * HD;
  const long rs = DIM;
  const long qrow0 = (long)b * TT + qt * 64 + wave * 16;

  u16x8 qf[4];
#pragma unroll
  for (int kkk = 0; kkk < 4; ++kkk)
    qf[kkk] = *(const u16x8*)(Q + (qrow0 + lrow) * rs + colBase + kkk * 32 + lgrp * 8);

  const f32x4 fz = {0.f, 0.f, 0.f, 0.f};
  f32x4 oacc[8];
#pragma unroll
  for (int nf = 0; nf < 8; ++nf) oacc[nf] = fz;
  float mst[4] = {-1e30f, -1e30f, -1e30f, -1e30f};
  float lst[4] = {0.f, 0.f, 0.f, 0.f};
  const float scale = 0.08838834764831845f;  // 1/sqrt(128)

  for (int kt2 = 0; kt2 < TT / 64; ++kt2) {
    const long krow = (long)b * TT + kt2 * 64;
    __syncthreads();   // all waves done reading prev Ks/Vs
#pragma unroll
    for (int i = 0; i < 4; ++i) {
      const int L = (i * 256 + tid) * 16;   // linear LDS byte position
      // K: stored[row][chunk] = logical[row][chunk ^ (row&7)]  (16B chunks)
      const int krw = L >> 8;
      const int ksc = ((L >> 4) & 15) ^ (krw & 7);
      load_lds_16B(K + (krow + krw) * rs + colBase + ksc * 8, (char*)Ks + L);
      // V: [d16 block][kv/4 sub][4][16] subtiles (subtile = 4 kv rows x 16 d)
      const int vbl = L >> 11;
      const int vkv = ((L >> 7) & 15) * 4 + ((L >> 5) & 3);
      const int vd  = vbl * 16 + ((L >> 4) & 1) * 8;
      load_lds_16B(V + (krow + vkv) * rs + colBase + vd, (char*)Vs + L);
    }
    __syncthreads();   // staged data visible (vmcnt drained by barrier)

    // S = Q K^T : 16x64 per wave
    f32x4 sacc[4];
#pragma unroll
    for (int n = 0; n < 4; ++n) sacc[n] = fz;
    __builtin_amdgcn_s_setprio(1);
#pragma unroll
    for (int kkk = 0; kkk < 4; ++kkk) {
#pragma unroll
      for (int n = 0; n < 4; ++n) {
        const int row = n * 16 + lrow;
        const int ch  = (kkk * 4 + lgrp) ^ (row & 7);
        u16x8 bfr = *(const u16x8*)((const char*)Ks + row * 256 + ch * 16);
        sacc[n] = mfma16(qf[kkk], bfr, sacc[n]);
      }
    }
    __builtin_amdgcn_s_setprio(0);
#pragma unroll
    for (int n = 0; n < 4; ++n) sacc[n] *= scale;

    // row max over 64 cols: 4 frags then 16-lane butterfly
    float rmax[4];
#pragma unroll
    for (int r = 0; r < 4; ++r)
      rmax[r] = fmaxf(fmaxf(sacc[0][r], sacc[1][r]), fmaxf(sacc[2][r], sacc[3][r]));
#pragma unroll
    for (int off = 8; off >= 1; off >>= 1)
#pragma unroll
      for (int r = 0; r < 4; ++r)
        rmax[r] = fmaxf(rmax[r], __shfl_xor(rmax[r], off, 64));

    float alpha[4];
#pragma unroll
    for (int r = 0; r < 4; ++r) {
      float mnew = fmaxf(mst[r], rmax[r]);
      alpha[r] = __expf(mst[r] - mnew);
      mst[r] = mnew;
    }
    float rsum[4] = {0.f, 0.f, 0.f, 0.f};
#pragma unroll
    for (int n = 0; n < 4; ++n)
#pragma unroll
      for (int r = 0; r < 4; ++r) {
        float pv = __expf(sacc[n][r] - mst[r]);
        rsum[r] += pv;
        Ps[wave][lgrp * 4 + r][n * 16 + lrow] = f2bf(pv);
      }
#pragma unroll
    for (int off = 8; off >= 1; off >>= 1)
#pragma unroll
      for (int r = 0; r < 4; ++r) rsum[r] += __shfl_xor(rsum[r], off, 64);
#pragma unroll
    for (int r = 0; r < 4; ++r) lst[r] = lst[r] * alpha[r] + rsum[r];
#pragma unroll
    for (int nf = 0; nf < 8; ++nf)
#pragma unroll
      for (int r = 0; r < 4; ++r) oacc[nf][r] *= alpha[r];

    // Ps write->read is same-wave cross-lane: wait for LDS writes to land.
    asm volatile("s_waitcnt lgkmcnt(0)" ::: "memory");

    // O += P V : P is 16x64 (per-wave LDS), V via HW-transpose reads.
    __builtin_amdgcn_s_setprio(1);
#pragma unroll
    for (int kk2 = 0; kk2 < 2; ++kk2) {
      u16x8 af = *(const u16x8*)&Ps[wave][lrow][kk2 * 32 + lgrp * 8];
#pragma unroll
      for (int nf = 0; nf < 8; ++nf) {
        // subtile pair for kv rows kk2*32+lgrp*8 .. +7, d cols nf*16..nf*16+15
        const int vbase = nf * 2048 + kk2 * 1024 + lgrp * 256 + lrow * 8;
        u16x4 lo, hi;
        trpair(Vs, vbase, lo, hi);
        u16x8 bfr;
        bfr[0] = lo[0]; bfr[1] = lo[1]; bfr[2] = lo[2]; bfr[3] = lo[3];
        bfr[4] = hi[0]; bfr[5] = hi[1]; bfr[6] = hi[2]; bfr[7] = hi[3];
        oacc[nf] = mfma16(af, bfr, oacc[nf]);
      }
    }
    __builtin_amdgcn_s_setprio(0);
  }

  float inv[4];
#pragma unroll
  for (int r = 0; r < 4; ++r) inv[r] = 1.0f / lst[r];
#pragma unroll
  for (int nf = 0; nf < 8; ++nf)
#pragma unroll
    for (int r = 0; r < 4; ++r)
      O[(qrow0 + lgrp * 4 + r) * rs + colBase + nf * 16 + lrow] =
          f2bf(oacc[nf][r] * inv[r]);
}

// ---------------- launch ----------------------------------------------------
extern "C" void kernel_launch(void* const* d_in, const int* in_sizes, int n_in,
                              void* d_out, int out_size, void* d_ws, size_t ws_size,
                              hipStream_t stream) {
  const float* x  = (const float*)d_in[0];
  const float* fc = (const float*)d_in[1];
  const float* fs = (const float*)d_in[2];
  const float* wq = (const float*)d_in[3];
  const float* wk = (const float*)d_in[4];
  const float* wv = (const float*)d_in[5];
  const float* wo = (const float*)d_in[6];
  float* out = (float*)d_out;

  // ws layout (bf16 elements). Needs 58,720,256 * 2B = 112 MiB of d_ws.
  uint16_t* w16 = (uint16_t*)d_ws;
  uint16_t* xb  = w16;                  // 8,388,608
  uint16_t* wqb = xb  + 8388608;        // 4,194,304
  uint16_t* wkb = wqb + 4194304;
  uint16_t* wvb = wkb + 4194304;
  uint16_t* wob = wvb + 4194304;
  uint16_t* qb  = wob + 4194304;        // 8,388,608 each
  uint16_t* kb  = qb  + 8388608;
  uint16_t* vb  = kb  + 8388608;
  uint16_t* ob  = vb  + 8388608;

  // casts
  cast_f32_bf16<<<8192, 256, 0, stream>>>(x,  xb,  8388608 / 4);
  cast_f32_bf16<<<4096, 256, 0, stream>>>(wq, wqb, 4194304 / 4);
  cast_f32_bf16<<<4096, 256, 0, stream>>>(wk, wkb, 4194304 / 4);
  cast_f32_bf16<<<4096, 256, 0, stream>>>(wv, wvb, 4194304 / 4);
  cast_f32_bf16<<<4096, 256, 0, stream>>>(wo, wob, 4194304 / 4);

  // QKV projections: (4096x2048) = xb @ w^T
  dim3 gp(DIM / 128, MR / 128);
  gemm_bt<0><<<gp, 256, 0, stream>>>(xb, wqb, nullptr, qb, MR, DIM, DIM);
  gemm_bt<0><<<gp, 256, 0, stream>>>(xb, wkb, nullptr, kb, MR, DIM, DIM);
  gemm_bt<0><<<gp, 256, 0, stream>>>(xb, wvb, nullptr, vb, MR, DIM, DIM);

  // RoPE on q,k
  rope_qk<<<(MR * (DIM / 2)) / 256, 256, 0, stream>>>(qb, kb, fc, fs);

  // attention
  dim3 ga(BB * NH, TT / 64);
  attn_fwd<<<ga, 256, 0, stream>>>(qb, kb, vb, ob);

  // output projection -> fp32 d_out
  gemm_bt<1><<<gp, 256, 0, stream>>>(ob, wob, out, nullptr, MR, DIM, DIM);
}

// Round 4
// 315.109 us; speedup vs baseline: 1.4724x; 1.0341x over previous
//
#include <hip/hip_runtime.h>
#include <stdint.h>

// Problem constants
#define BB 4
#define TT 1024
#define DIM 2048
#define NH 16
#define HD 128
#define MR 4096   // BB*TT rows
#define QKVS (3 * DIM)   // 6144: row stride of fused qkv buffer

typedef __attribute__((ext_vector_type(4))) float    f32x4;
typedef __attribute__((ext_vector_type(8))) uint16_t u16x8;
typedef __attribute__((ext_vector_type(4))) uint16_t u16x4;
typedef __attribute__((ext_vector_type(4))) short    s16x4;
typedef __attribute__((ext_vector_type(8))) __bf16   bf16x8;

static __device__ __forceinline__ uint16_t f2bf(float f) {
  uint32_t u = __builtin_bit_cast(uint32_t, f);
  u += 0x7fffu + ((u >> 16) & 1u);   // round-to-nearest-even
  return (uint16_t)(u >> 16);
}
static __device__ __forceinline__ float bf2f(uint16_t b) {
  uint32_t u = ((uint32_t)b) << 16;
  return __builtin_bit_cast(float, u);
}

static __device__ __forceinline__ f32x4 mfma16(u16x8 a, u16x8 b, f32x4 c) {
  return __builtin_amdgcn_mfma_f32_16x16x32_bf16(
      __builtin_bit_cast(bf16x8, a), __builtin_bit_cast(bf16x8, b), c, 0, 0, 0);
}

// async global->LDS, 16B per lane; LDS dest = wave-uniform base + lane*16
static __device__ __forceinline__ void load_lds_16B(const void* g, void* l) {
  __builtin_amdgcn_global_load_lds(
      (const __attribute__((address_space(1))) void*)g,
      (__attribute__((address_space(3))) void*)l, 16, 0, 0);
}

// paired hardware transpose reads at byteoff and byteoff+128.
// Each lane fetches 8B at ITS OWN address; the 16-lane group's 128B forms a
// 4x16 bf16 row-major tile; lane l receives column (l&15).
static __device__ __forceinline__ void trpair(const uint16_t* base, int byteoff,
                                              u16x4& lo, u16x4& hi) {
  __attribute__((address_space(3))) char* ap =
      (__attribute__((address_space(3))) char*)(void*)base + byteoff;
#if defined(__has_builtin) && __has_builtin(__builtin_amdgcn_ds_read_tr16_b64_v4i16)
  s16x4 r0 = __builtin_amdgcn_ds_read_tr16_b64_v4i16(
      (__attribute__((address_space(3))) s16x4*)ap);
  s16x4 r1 = __builtin_amdgcn_ds_read_tr16_b64_v4i16(
      (__attribute__((address_space(3))) s16x4*)(ap + 128));
  lo = __builtin_bit_cast(u16x4, r0);
  hi = __builtin_bit_cast(u16x4, r1);
#else
  uint32_t a32 = (uint32_t)(uintptr_t)ap;
  asm volatile("ds_read_b64_tr_b16 %0, %2\n\t"
               "ds_read_b64_tr_b16 %1, %2 offset:128\n\t"
               "s_waitcnt lgkmcnt(0)"
               : "=&v"(lo), "=&v"(hi) : "v"(a32));
#endif
}

// ---------------- casts fp32 -> bf16 (vectorized) ----------------
__global__ __launch_bounds__(256) void cast_f32_bf16(const float* __restrict__ in,
                                                     uint16_t* __restrict__ out, int n4) {
  int i = blockIdx.x * 256 + threadIdx.x;
  if (i >= n4) return;
  f32x4 v = ((const f32x4*)in)[i];
  u16x4 o;
  o[0] = f2bf(v[0]); o[1] = f2bf(v[1]); o[2] = f2bf(v[2]); o[3] = f2bf(v[3]);
  ((u16x4*)out)[i] = o;
}

// three equal-size sources -> one contiguous dest (wq|wk|wv)
__global__ __launch_bounds__(256) void cast3_f32_bf16(const float* __restrict__ s0,
                                                      const float* __restrict__ s1,
                                                      const float* __restrict__ s2,
                                                      uint16_t* __restrict__ out) {
  const int per = 4194304 / 4;   // f32x4 chunks per matrix
  int i = blockIdx.x * 256 + threadIdx.x;          // [0, 3*per)
  const float* src = (i < per) ? s0 : (i < 2 * per) ? s1 : s2;
  int j = (i < per) ? i : (i < 2 * per) ? (i - per) : (i - 2 * per);
  f32x4 v = ((const f32x4*)src)[j];
  u16x4 o;
  o[0] = f2bf(v[0]); o[1] = f2bf(v[1]); o[2] = f2bf(v[2]); o[3] = f2bf(v[3]);
  ((u16x4*)out)[i] = o;
}

// ---------------- GEMM: C[M,N] = A[M,K] * Bt[N,K]^T (both row-major bf16) ----
// 128x128 tile, BK=64, 256 threads = 4 waves (2x2), each wave 64x64 = 4x4 MFMA frags.
template <int OUTF32>
__global__ __launch_bounds__(256) void gemm_bt(const uint16_t* __restrict__ A,
                                               const uint16_t* __restrict__ Bt,
                                               float* __restrict__ Cf,
                                               uint16_t* __restrict__ Cb,
                                               int M, int N, int K) {
  __shared__ __attribute__((aligned(16))) uint16_t As[128][64];
  __shared__ __attribute__((aligned(16))) uint16_t Bs[128][64];
  const int tid  = threadIdx.x;
  const int lane = tid & 63;
  const int wave = tid >> 6;
  const int wr   = (wave >> 1) * 64;
  const int wc   = (wave & 1) * 64;
  const int lrow = lane & 15;
  const int lgrp = lane >> 4;
  const long bRow = (long)blockIdx.y * 128;
  const long bCol = (long)blockIdx.x * 128;

  const f32x4 fz = {0.f, 0.f, 0.f, 0.f};
  f32x4 acc[4][4];
#pragma unroll
  for (int m = 0; m < 4; ++m)
#pragma unroll
    for (int n = 0; n < 4; ++n) acc[m][n] = fz;

  const int srow = tid >> 3;        // 0..31
  const int scol = (tid & 7) * 8;   // 0..56
  const int nkt = K >> 6;
  for (int kt = 0; kt < nkt; ++kt) {
    const int kb = kt << 6;
    __syncthreads();
#pragma unroll
    for (int i = 0; i < 4; ++i) {
      load_lds_16B(A  + (bRow + srow + i * 32) * (long)K + kb + scol,
                   &As[0][0] + (size_t)(i * 256 + tid) * 8);
      load_lds_16B(Bt + (bCol + srow + i * 32) * (long)K + kb + scol,
                   &Bs[0][0] + (size_t)(i * 256 + tid) * 8);
    }
    __syncthreads();
#pragma unroll
    for (int kk = 0; kk < 2; ++kk) {
      const int ko = kk * 32 + lgrp * 8;
      u16x8 af[4], bf[4];
#pragma unroll
      for (int m = 0; m < 4; ++m) af[m] = *(const u16x8*)&As[wr + m * 16 + lrow][ko];
#pragma unroll
      for (int n = 0; n < 4; ++n) bf[n] = *(const u16x8*)&Bs[wc + n * 16 + lrow][ko];
#pragma unroll
      for (int m = 0; m < 4; ++m)
#pragma unroll
        for (int n = 0; n < 4; ++n) acc[m][n] = mfma16(af[m], bf[n], acc[m][n]);
    }
  }
#pragma unroll
  for (int m = 0; m < 4; ++m)
#pragma unroll
    for (int n = 0; n < 4; ++n) {
      const long grow0 = bRow + wr + m * 16 + lgrp * 4;
      const long gcol  = bCol + wc + n * 16 + lrow;
#pragma unroll
      for (int r = 0; r < 4; ++r) {
        const long idx = (grow0 + r) * (long)N + gcol;
        if (OUTF32) Cf[idx] = acc[m][n][r];
        else        Cb[idx] = f2bf(acc[m][n][r]);
      }
    }
}

// ---------------- RoPE in-place on fused qkv (q and k halves) ---------------
__global__ __launch_bounds__(256) void rope_qk(uint16_t* __restrict__ qkv,
                                               const float* __restrict__ cosT,
                                               const float* __restrict__ sinT) {
  const int p = blockIdx.x * 256 + threadIdx.x;   // [0, MR * DIM/2)
  if (p >= MR * (DIM / 2)) return;
  const int row = p >> 10;          // DIM/2 = 1024 pairs per row
  const int j   = p & 1023;
  const int h   = j >> 6;           // 64 pairs per head
  const int fi  = j & 63;
  const int t   = row & (TT - 1);
  const float c = cosT[t * 64 + fi];
  const float s = sinT[t * 64 + fi];
  const long off = (long)row * QKVS + h * HD + fi * 2;

  uint32_t qp = *(uint32_t*)(qkv + off);
  float qe = bf2f((uint16_t)(qp & 0xffff));
  float qo = bf2f((uint16_t)(qp >> 16));
  *(uint32_t*)(qkv + off) =
      (uint32_t)f2bf(qe * c - qo * s) | ((uint32_t)f2bf(qe * s + qo * c) << 16);

  uint32_t kp = *(uint32_t*)(qkv + DIM + off);
  float ke = bf2f((uint16_t)(kp & 0xffff));
  float ko = bf2f((uint16_t)(kp >> 16));
  *(uint32_t*)(qkv + DIM + off) =
      (uint32_t)f2bf(ke * c - ko * s) | ((uint32_t)f2bf(ke * s + ko * c) << 16);
}

// ---------------- Flash attention fwd ---------------------------------------
// grid (BB*NH, TT/64). 256 threads = 4 waves; each wave owns 16 q-rows.
// Double-buffered K/V staging with counted vmcnt + raw barriers (T3/T4):
// stage(t+1) issued before compute(t); s_waitcnt vmcnt(8) waits only tile t's
// loads; t+1's 8 loads stay in flight under compute. Raw s_barrier (NOT
// __syncthreads) so the compiler doesn't re-insert a vmcnt(0) drain.
// K swizzled (chunk^row&7), V subtiled for ds_read_b64_tr_b16, defer-max (T13).
__global__ __launch_bounds__(256) void attn_fwd(const uint16_t* __restrict__ Q,
                                                const uint16_t* __restrict__ K,
                                                const uint16_t* __restrict__ V,
                                                uint16_t* __restrict__ O) {
  __shared__ __attribute__((aligned(16))) uint16_t Ks[2][64 * 128];  // 2x16 KB
  __shared__ __attribute__((aligned(16))) uint16_t Vs[2][64 * 128];  // 2x16 KB
  __shared__ __attribute__((aligned(16))) uint16_t Ps[4][16][72];    // 9 KB
  const int tid  = threadIdx.x;
  const int lane = tid & 63;
  const int wave = tid >> 6;
  const int lrow = lane & 15;
  const int lgrp = lane >> 4;
  const int b  = blockIdx.x >> 4;
  const int h  = blockIdx.x & 15;
  const int qt = blockIdx.y;
  const long colBase = (long)h * HD;
  const long rs = QKVS;      // q/k/v row stride (fused buffer)
  const long os = DIM;       // output row stride
  const long qrow0 = (long)b * TT + qt * 64 + wave * 16;

  u16x8 qf[4];
#pragma unroll
  for (int kkk = 0; kkk < 4; ++kkk)
    qf[kkk] = *(const u16x8*)(Q + (qrow0 + lrow) * rs + colBase + kkk * 32 + lgrp * 8);

  const f32x4 fz = {0.f, 0.f, 0.f, 0.f};
  f32x4 oacc[8];
#pragma unroll
  for (int nf = 0; nf < 8; ++nf) oacc[nf] = fz;
  float mst[4] = {-1e30f, -1e30f, -1e30f, -1e30f};
  float lst[4] = {0.f, 0.f, 0.f, 0.f};
  const float scale = 0.08838834764831845f;  // 1/sqrt(128)

  auto stage = [&](int kt, int buf) {
    const long krow = (long)b * TT + kt * 64;
#pragma unroll
    for (int i = 0; i < 4; ++i) {
      const int L = (i * 256 + tid) * 16;   // buf-relative linear byte position
      // K: stored[row][chunk] = logical[row][chunk ^ (row&7)]  (16B chunks)
      const int krw = L >> 8;
      const int ksc = ((L >> 4) & 15) ^ (krw & 7);
      load_lds_16B(K + (krow + krw) * rs + colBase + ksc * 8,
                   (char*)&Ks[buf][0] + L);
      // V: [d16 block][kv/4 sub][4][16] subtiles (subtile = 4 kv rows x 16 d)
      const int vbl = L >> 11;
      const int vkv = ((L >> 7) & 15) * 4 + ((L >> 5) & 3);
      const int vd  = vbl * 16 + ((L >> 4) & 1) * 8;
      load_lds_16B(V + (krow + vkv) * rs + colBase + vd,
                   (char*)&Vs[buf][0] + L);
    }
  };

  stage(0, 0);   // prologue: 8 loads in flight

  for (int kt2 = 0; kt2 < TT / 64; ++kt2) {
    const int cur = kt2 & 1;
    if (kt2 < TT / 64 - 1) {
      stage(kt2 + 1, cur ^ 1);                          // 8 more in flight
      asm volatile("s_waitcnt vmcnt(8)" ::: "memory");  // tile kt2's loads done
    } else {
      asm volatile("s_waitcnt vmcnt(0)" ::: "memory");
    }
    __builtin_amdgcn_s_barrier();   // raw: no compiler vmcnt(0) drain

    // S = Q K^T : 16x64 per wave
    f32x4 sacc[4];
#pragma unroll
    for (int n = 0; n < 4; ++n) sacc[n] = fz;
    __builtin_amdgcn_s_setprio(1);
#pragma unroll
    for (int kkk = 0; kkk < 4; ++kkk) {
#pragma unroll
      for (int n = 0; n < 4; ++n) {
        const int row = n * 16 + lrow;
        const int ch  = (kkk * 4 + lgrp) ^ (row & 7);
        u16x8 bfr = *(const u16x8*)((const char*)&Ks[cur][0] + row * 256 + ch * 16);
        sacc[n] = mfma16(qf[kkk], bfr, sacc[n]);
      }
    }
    __builtin_amdgcn_s_setprio(0);
#pragma unroll
    for (int n = 0; n < 4; ++n) sacc[n] *= scale;

    // row max over 64 cols: 4 frags then 16-lane butterfly
    float rmax[4];
#pragma unroll
    for (int r = 0; r < 4; ++r)
      rmax[r] = fmaxf(fmaxf(sacc[0][r], sacc[1][r]), fmaxf(sacc[2][r], sacc[3][r]));
#pragma unroll
    for (int off = 8; off >= 1; off >>= 1)
#pragma unroll
      for (int r = 0; r < 4; ++r)
        rmax[r] = fmaxf(rmax[r], __shfl_xor(rmax[r], off, 64));

    // defer-max (T13): rescale only when max grew past threshold
    bool need = false;
#pragma unroll
    for (int r = 0; r < 4; ++r) need = need || (rmax[r] > mst[r] + 8.0f);
    if (__any(need)) {
#pragma unroll
      for (int r = 0; r < 4; ++r) {
        float mnew  = fmaxf(mst[r], rmax[r]);
        float alpha = __expf(mst[r] - mnew);
        mst[r] = mnew;
        lst[r] *= alpha;
#pragma unroll
        for (int nf = 0; nf < 8; ++nf) oacc[nf][r] *= alpha;
      }
    }

    float rsum[4] = {0.f, 0.f, 0.f, 0.f};
#pragma unroll
    for (int n = 0; n < 4; ++n)
#pragma unroll
      for (int r = 0; r < 4; ++r) {
        float pv = __expf(sacc[n][r] - mst[r]);   // bounded by e^8
        rsum[r] += pv;
        Ps[wave][lgrp * 4 + r][n * 16 + lrow] = f2bf(pv);
      }
#pragma unroll
    for (int off = 8; off >= 1; off >>= 1)
#pragma unroll
      for (int r = 0; r < 4; ++r) rsum[r] += __shfl_xor(rsum[r], off, 64);
#pragma unroll
    for (int r = 0; r < 4; ++r) lst[r] += rsum[r];

    // Ps write->read is same-wave cross-lane: wait for LDS writes to land.
    asm volatile("s_waitcnt lgkmcnt(0)" ::: "memory");

    // O += P V : P is 16x64 (per-wave LDS), V via HW-transpose reads.
    __builtin_amdgcn_s_setprio(1);
#pragma unroll
    for (int kk2 = 0; kk2 < 2; ++kk2) {
      u16x8 af = *(const u16x8*)&Ps[wave][lrow][kk2 * 32 + lgrp * 8];
#pragma unroll
      for (int nf = 0; nf < 8; ++nf) {
        const int vbase = nf * 2048 + kk2 * 1024 + lgrp * 256 + lrow * 8;
        u16x4 lo, hi;
        trpair(&Vs[cur][0], vbase, lo, hi);
        u16x8 bfr;
        bfr[0] = lo[0]; bfr[1] = lo[1]; bfr[2] = lo[2]; bfr[3] = lo[3];
        bfr[4] = hi[0]; bfr[5] = hi[1]; bfr[6] = hi[2]; bfr[7] = hi[3];
        oacc[nf] = mfma16(af, bfr, oacc[nf]);
      }
    }
    __builtin_amdgcn_s_setprio(0);

    __builtin_amdgcn_s_barrier();   // all waves done with buf[cur] before restage
  }

  float inv[4];
#pragma unroll
  for (int r = 0; r < 4; ++r) inv[r] = 1.0f / lst[r];
#pragma unroll
  for (int nf = 0; nf < 8; ++nf)
#pragma unroll
    for (int r = 0; r < 4; ++r)
      O[(qrow0 + lgrp * 4 + r) * os + colBase + nf * 16 + lrow] =
          f2bf(oacc[nf][r] * inv[r]);
}

// ---------------- launch ----------------------------------------------------
extern "C" void kernel_launch(void* const* d_in, const int* in_sizes, int n_in,
                              void* d_out, int out_size, void* d_ws, size_t ws_size,
                              hipStream_t stream) {
  const float* x  = (const float*)d_in[0];
  const float* fc = (const float*)d_in[1];
  const float* fs = (const float*)d_in[2];
  const float* wq = (const float*)d_in[3];
  const float* wk = (const float*)d_in[4];
  const float* wv = (const float*)d_in[5];
  const float* wo = (const float*)d_in[6];
  float* out = (float*)d_out;

  // ws layout (bf16 elements), total 58,720,256 elems = 112 MiB.
  uint16_t* w16  = (uint16_t*)d_ws;
  uint16_t* xb   = w16;                   //  8,388,608  x  [4096][2048]
  uint16_t* wqkv = xb + 8388608;          // 12,582,912  [6144][2048] (wq|wk|wv)
  uint16_t* wob  = wqkv + 12582912;       //  4,194,304  [2048][2048]
  uint16_t* qkv  = wob + 4194304;         // 25,165,824  [4096][6144] (q|k|v)
  uint16_t* ob   = qkv + 25165824;        //  8,388,608  [4096][2048]

  // casts
  cast_f32_bf16<<<8192, 256, 0, stream>>>(x, xb, 8388608 / 4);
  cast3_f32_bf16<<<3 * 4096, 256, 0, stream>>>(wq, wk, wv, wqkv);
  cast_f32_bf16<<<4096, 256, 0, stream>>>(wo, wob, 4194304 / 4);

  // fused QKV projection: [4096][6144] = xb @ wqkv^T
  dim3 gqkv(QKVS / 128, MR / 128);
  gemm_bt<0><<<gqkv, 256, 0, stream>>>(xb, wqkv, nullptr, qkv, MR, QKVS, DIM);

  // RoPE on q,k halves of qkv
  rope_qk<<<(MR * (DIM / 2)) / 256, 256, 0, stream>>>(qkv, fc, fs);

  // attention: Q,K,V strided views into qkv
  dim3 ga(BB * NH, TT / 64);
  attn_fwd<<<ga, 256, 0, stream>>>(qkv, qkv + DIM, qkv + 2 * DIM, ob);

  // output projection -> fp32 d_out
  dim3 gp(DIM / 128, MR / 128);
  gemm_bt<1><<<gp, 256, 0, stream>>>(ob, wob, out, nullptr, MR, DIM, DIM);
}

// Round 5
// 300.878 us; speedup vs baseline: 1.5421x; 1.0473x over previous
//
#include <hip/hip_runtime.h>
#include <stdint.h>

// Problem constants
#define BB 4
#define TT 1024
#define DIM 2048
#define NH 16
#define HD 128
#define MR 4096   // BB*TT rows
#define QKVS (3 * DIM)   // 6144: row stride of fused qkv buffer

typedef __attribute__((ext_vector_type(4))) float    f32x4;
typedef __attribute__((ext_vector_type(8))) uint16_t u16x8;
typedef __attribute__((ext_vector_type(4))) uint16_t u16x4;
typedef __attribute__((ext_vector_type(4))) short    s16x4;
typedef __attribute__((ext_vector_type(8))) __bf16   bf16x8;

static __device__ __forceinline__ uint16_t f2bf(float f) {
  uint32_t u = __builtin_bit_cast(uint32_t, f);
  u += 0x7fffu + ((u >> 16) & 1u);   // round-to-nearest-even
  return (uint16_t)(u >> 16);
}
static __device__ __forceinline__ float bf2f(uint16_t b) {
  uint32_t u = ((uint32_t)b) << 16;
  return __builtin_bit_cast(float, u);
}

static __device__ __forceinline__ f32x4 mfma16(u16x8 a, u16x8 b, f32x4 c) {
  return __builtin_amdgcn_mfma_f32_16x16x32_bf16(
      __builtin_bit_cast(bf16x8, a), __builtin_bit_cast(bf16x8, b), c, 0, 0, 0);
}

// async global->LDS, 16B per lane; LDS dest = wave-uniform base + lane*16
static __device__ __forceinline__ void load_lds_16B(const void* g, void* l) {
  __builtin_amdgcn_global_load_lds(
      (const __attribute__((address_space(1))) void*)g,
      (__attribute__((address_space(3))) void*)l, 16, 0, 0);
}

// paired hardware transpose reads at byteoff and byteoff+128.
static __device__ __forceinline__ void trpair(const uint16_t* base, int byteoff,
                                              u16x4& lo, u16x4& hi) {
  __attribute__((address_space(3))) char* ap =
      (__attribute__((address_space(3))) char*)(void*)base + byteoff;
#if defined(__has_builtin) && __has_builtin(__builtin_amdgcn_ds_read_tr16_b64_v4i16)
  s16x4 r0 = __builtin_amdgcn_ds_read_tr16_b64_v4i16(
      (__attribute__((address_space(3))) s16x4*)ap);
  s16x4 r1 = __builtin_amdgcn_ds_read_tr16_b64_v4i16(
      (__attribute__((address_space(3))) s16x4*)(ap + 128));
  lo = __builtin_bit_cast(u16x4, r0);
  hi = __builtin_bit_cast(u16x4, r1);
#else
  uint32_t a32 = (uint32_t)(uintptr_t)ap;
  asm volatile("ds_read_b64_tr_b16 %0, %2\n\t"
               "ds_read_b64_tr_b16 %1, %2 offset:128\n\t"
               "s_waitcnt lgkmcnt(0)"
               : "=&v"(lo), "=&v"(hi) : "v"(a32));
#endif
}

// ---------------- casts fp32 -> bf16 (vectorized) ----------------
__global__ __launch_bounds__(256) void cast_f32_bf16(const float* __restrict__ in,
                                                     uint16_t* __restrict__ out, int n4) {
  int i = blockIdx.x * 256 + threadIdx.x;
  if (i >= n4) return;
  f32x4 v = ((const f32x4*)in)[i];
  u16x4 o;
  o[0] = f2bf(v[0]); o[1] = f2bf(v[1]); o[2] = f2bf(v[2]); o[3] = f2bf(v[3]);
  ((u16x4*)out)[i] = o;
}

// three equal-size sources -> one contiguous dest (wq|wk|wv)
__global__ __launch_bounds__(256) void cast3_f32_bf16(const float* __restrict__ s0,
                                                      const float* __restrict__ s1,
                                                      const float* __restrict__ s2,
                                                      uint16_t* __restrict__ out) {
  const int per = 4194304 / 4;   // f32x4 chunks per matrix
  int i = blockIdx.x * 256 + threadIdx.x;          // [0, 3*per)
  const float* src = (i < per) ? s0 : (i < 2 * per) ? s1 : s2;
  int j = (i < per) ? i : (i < 2 * per) ? (i - per) : (i - 2 * per);
  f32x4 v = ((const f32x4*)src)[j];
  u16x4 o;
  o[0] = f2bf(v[0]); o[1] = f2bf(v[1]); o[2] = f2bf(v[2]); o[3] = f2bf(v[3]);
  ((u16x4*)out)[i] = o;
}

// ---------------- GEMM 256x256: C[M,N] = A[M,K] * Bt[N,K]^T (bf16) -----------
// 512 threads = 8 waves (2Mx4N); per-wave C = 128x64 = 8x4 16x16 frags.
// Dynamic LDS 128 KiB: dbuf x (A 256x64 + B 256x64), both XOR-swizzled
// (stored chunk = c ^ (row&7), 16B chunks) via pre-swizzled global source.
// Counted-vmcnt double-buffer: tile t+1 always in flight; stage(t+2) issued
// after mid-iter barrier (all reads of buf cur complete). vmcnt never 0 in
// steady state. Raw s_barrier to avoid compiler vmcnt(0) drain.
template <int OUTF32>
__global__ __launch_bounds__(512, 2) void gemm256(const uint16_t* __restrict__ A,
                                                  const uint16_t* __restrict__ Bt,
                                                  float* __restrict__ Cf,
                                                  uint16_t* __restrict__ Cb,
                                                  int M, int N, int K) {
  extern __shared__ __attribute__((aligned(16))) uint16_t smem[];  // 2*65536B
  const int tid  = threadIdx.x;
  const int lane = tid & 63;
  const int wave = tid >> 6;          // 0..7
  const int lrow = lane & 15;
  const int lgrp = lane >> 4;
  const int wr   = (wave >> 2) * 128; // 0 / 128
  const int wc   = (wave & 3) * 64;   // 0,64,128,192

  // T1: XCD-aware block swizzle (grid % 8 == 0 for both our launches)
  const int nbx = N >> 8, nby = M >> 8;
  const int nwg = nbx * nby;
  const int wg  = ((int)blockIdx.x % 8) * (nwg / 8) + (int)blockIdx.x / 8;
  const long bRow = (long)(wg / nbx) << 8;
  const long bCol = (long)(wg % nbx) << 8;

  const f32x4 fz = {0.f, 0.f, 0.f, 0.f};
  f32x4 acc[8][4];
#pragma unroll
  for (int m = 0; m < 8; ++m)
#pragma unroll
    for (int n = 0; n < 4; ++n) acc[m][n] = fz;

  const int NT = K >> 6;
  // stage one 64-K tile (A 32KB + B 32KB) into buf; 8 gload_lds per thread-ish
  // (4 A + 4 B instructions per wave, 16B/lane). Pre-swizzled source column.
  const int srow8 = tid >> 3;        // row progresses 64 per issue
  const int sc    = ((tid & 7) ^ (srow8 & 7)) * 8;  // swizzled col (elems)
  auto stage = [&](int kt, int buf) {
    const long kb = (long)kt << 6;
    char* Ab = (char*)smem + buf * 65536;
    char* Bb = Ab + 32768;
#pragma unroll
    for (int i = 0; i < 4; ++i) {
      const int row = i * 64 + srow8;
      const int L   = (i * 512 + tid) * 16;
      load_lds_16B(A + (bRow + row) * (long)K + kb + sc, Ab + L);
    }
#pragma unroll
    for (int i = 0; i < 4; ++i) {
      const int row = i * 64 + srow8;
      const int L   = (i * 512 + tid) * 16;
      load_lds_16B(Bt + (bCol + row) * (long)K + kb + sc, Bb + L);
    }
  };

  stage(0, 0);
  stage(1, 1);

  for (int kt = 0; kt < NT; ++kt) {
    const int cur = kt & 1;
    if (kt == NT - 1) asm volatile("s_waitcnt vmcnt(0)" ::: "memory");
    else              asm volatile("s_waitcnt vmcnt(8)" ::: "memory");
    __builtin_amdgcn_s_barrier();   // tile kt landed everywhere; bufs coherent

    const char* Ab = (const char*)smem + cur * 65536;
    const char* Bb = Ab + 32768;
    const int chA = lgrp ^ (lrow & 7);        // kk=0 chunk
    const int chB = (4 + lgrp) ^ (lrow & 7);  // kk=1 chunk

    // ---- kk = 0 ----
    u16x8 a0[8], b0[4];
#pragma unroll
    for (int m = 0; m < 8; ++m)
      a0[m] = *(const u16x8*)(Ab + (wr + m * 16 + lrow) * 128 + chA * 16);
#pragma unroll
    for (int n = 0; n < 4; ++n)
      b0[n] = *(const u16x8*)(Bb + (wc + n * 16 + lrow) * 128 + chA * 16);
    __builtin_amdgcn_s_setprio(1);
#pragma unroll
    for (int m = 0; m < 8; ++m)
#pragma unroll
      for (int n = 0; n < 4; ++n) acc[m][n] = mfma16(a0[m], b0[n], acc[m][n]);
    __builtin_amdgcn_s_setprio(0);

    // ---- kk = 1 ----
    u16x8 a1[8], b1[4];
#pragma unroll
    for (int m = 0; m < 8; ++m)
      a1[m] = *(const u16x8*)(Ab + (wr + m * 16 + lrow) * 128 + chB * 16);
#pragma unroll
    for (int n = 0; n < 4; ++n)
      b1[n] = *(const u16x8*)(Bb + (wc + n * 16 + lrow) * 128 + chB * 16);

    // all reads of buf cur are complete after this wait+barrier
    asm volatile("s_waitcnt lgkmcnt(0)" ::: "memory");
    __builtin_amdgcn_s_barrier();
    if (kt + 2 < NT) stage(kt + 2, cur);   // overwrite cur; overlaps MFMAs below

    __builtin_amdgcn_s_setprio(1);
#pragma unroll
    for (int m = 0; m < 8; ++m)
#pragma unroll
      for (int n = 0; n < 4; ++n) acc[m][n] = mfma16(a1[m], b1[n], acc[m][n]);
    __builtin_amdgcn_s_setprio(0);
  }

  // epilogue
#pragma unroll
  for (int m = 0; m < 8; ++m)
#pragma unroll
    for (int n = 0; n < 4; ++n) {
      const long grow0 = bRow + wr + m * 16 + lgrp * 4;
      const long gcol  = bCol + wc + n * 16 + lrow;
#pragma unroll
      for (int r = 0; r < 4; ++r) {
        const long idx = (grow0 + r) * (long)N + gcol;
        if (OUTF32) Cf[idx] = acc[m][n][r];
        else        Cb[idx] = f2bf(acc[m][n][r]);
      }
    }
}

// ---------------- RoPE in-place on fused qkv (q and k halves) ---------------
__global__ __launch_bounds__(256) void rope_qk(uint16_t* __restrict__ qkv,
                                               const float* __restrict__ cosT,
                                               const float* __restrict__ sinT) {
  const int p = blockIdx.x * 256 + threadIdx.x;   // [0, MR * DIM/2)
  if (p >= MR * (DIM / 2)) return;
  const int row = p >> 10;          // DIM/2 = 1024 pairs per row
  const int j   = p & 1023;
  const int h   = j >> 6;           // 64 pairs per head
  const int fi  = j & 63;
  const int t   = row & (TT - 1);
  const float c = cosT[t * 64 + fi];
  const float s = sinT[t * 64 + fi];
  const long off = (long)row * QKVS + h * HD + fi * 2;

  uint32_t qp = *(uint32_t*)(qkv + off);
  float qe = bf2f((uint16_t)(qp & 0xffff));
  float qo = bf2f((uint16_t)(qp >> 16));
  *(uint32_t*)(qkv + off) =
      (uint32_t)f2bf(qe * c - qo * s) | ((uint32_t)f2bf(qe * s + qo * c) << 16);

  uint32_t kp = *(uint32_t*)(qkv + DIM + off);
  float ke = bf2f((uint16_t)(kp & 0xffff));
  float ko = bf2f((uint16_t)(kp >> 16));
  *(uint32_t*)(qkv + DIM + off) =
      (uint32_t)f2bf(ke * c - ko * s) | ((uint32_t)f2bf(ke * s + ko * c) << 16);
}

// ---------------- Flash attention fwd ---------------------------------------
// grid (BB*NH, TT/64). 256 threads = 4 waves; each wave owns 16 q-rows.
// Counted-vmcnt double-buffered K/V staging; raw barriers; K XOR-swizzled;
// V subtiled for ds_read_b64_tr_b16; defer-max (T13).
__global__ __launch_bounds__(256) void attn_fwd(const uint16_t* __restrict__ Q,
                                                const uint16_t* __restrict__ K,
                                                const uint16_t* __restrict__ V,
                                                uint16_t* __restrict__ O) {
  __shared__ __attribute__((aligned(16))) uint16_t Ks[2][64 * 128];  // 2x16 KB
  __shared__ __attribute__((aligned(16))) uint16_t Vs[2][64 * 128];  // 2x16 KB
  __shared__ __attribute__((aligned(16))) uint16_t Ps[4][16][72];    // 9 KB
  const int tid  = threadIdx.x;
  const int lane = tid & 63;
  const int wave = tid >> 6;
  const int lrow = lane & 15;
  const int lgrp = lane >> 4;
  const int b  = blockIdx.x >> 4;
  const int h  = blockIdx.x & 15;
  const int qt = blockIdx.y;
  const long colBase = (long)h * HD;
  const long rs = QKVS;      // q/k/v row stride (fused buffer)
  const long os = DIM;       // output row stride
  const long qrow0 = (long)b * TT + qt * 64 + wave * 16;

  u16x8 qf[4];
#pragma unroll
  for (int kkk = 0; kkk < 4; ++kkk)
    qf[kkk] = *(const u16x8*)(Q + (qrow0 + lrow) * rs + colBase + kkk * 32 + lgrp * 8);

  const f32x4 fz = {0.f, 0.f, 0.f, 0.f};
  f32x4 oacc[8];
#pragma unroll
  for (int nf = 0; nf < 8; ++nf) oacc[nf] = fz;
  float mst[4] = {-1e30f, -1e30f, -1e30f, -1e30f};
  float lst[4] = {0.f, 0.f, 0.f, 0.f};
  const float scale = 0.08838834764831845f;  // 1/sqrt(128)

  auto stage = [&](int kt, int buf) {
    const long krow = (long)b * TT + kt * 64;
#pragma unroll
    for (int i = 0; i < 4; ++i) {
      const int L = (i * 256 + tid) * 16;   // buf-relative linear byte position
      const int krw = L >> 8;
      const int ksc = ((L >> 4) & 15) ^ (krw & 7);
      load_lds_16B(K + (krow + krw) * rs + colBase + ksc * 8,
                   (char*)&Ks[buf][0] + L);
      const int vbl = L >> 11;
      const int vkv = ((L >> 7) & 15) * 4 + ((L >> 5) & 3);
      const int vd  = vbl * 16 + ((L >> 4) & 1) * 8;
      load_lds_16B(V + (krow + vkv) * rs + colBase + vd,
                   (char*)&Vs[buf][0] + L);
    }
  };

  stage(0, 0);   // prologue: 8 loads in flight

  for (int kt2 = 0; kt2 < TT / 64; ++kt2) {
    const int cur = kt2 & 1;
    if (kt2 < TT / 64 - 1) {
      stage(kt2 + 1, cur ^ 1);                          // 8 more in flight
      asm volatile("s_waitcnt vmcnt(8)" ::: "memory");  // tile kt2's loads done
    } else {
      asm volatile("s_waitcnt vmcnt(0)" ::: "memory");
    }
    __builtin_amdgcn_s_barrier();   // raw: no compiler vmcnt(0) drain

    // S = Q K^T : 16x64 per wave
    f32x4 sacc[4];
#pragma unroll
    for (int n = 0; n < 4; ++n) sacc[n] = fz;
    __builtin_amdgcn_s_setprio(1);
#pragma unroll
    for (int kkk = 0; kkk < 4; ++kkk) {
#pragma unroll
      for (int n = 0; n < 4; ++n) {
        const int row = n * 16 + lrow;
        const int ch  = (kkk * 4 + lgrp) ^ (row & 7);
        u16x8 bfr = *(const u16x8*)((const char*)&Ks[cur][0] + row * 256 + ch * 16);
        sacc[n] = mfma16(qf[kkk], bfr, sacc[n]);
      }
    }
    __builtin_amdgcn_s_setprio(0);
#pragma unroll
    for (int n = 0; n < 4; ++n) sacc[n] *= scale;

    // row max over 64 cols: 4 frags then 16-lane butterfly
    float rmax[4];
#pragma unroll
    for (int r = 0; r < 4; ++r)
      rmax[r] = fmaxf(fmaxf(sacc[0][r], sacc[1][r]), fmaxf(sacc[2][r], sacc[3][r]));
#pragma unroll
    for (int off = 8; off >= 1; off >>= 1)
#pragma unroll
      for (int r = 0; r < 4; ++r)
        rmax[r] = fmaxf(rmax[r], __shfl_xor(rmax[r], off, 64));

    // defer-max (T13): rescale only when max grew past threshold
    bool need = false;
#pragma unroll
    for (int r = 0; r < 4; ++r) need = need || (rmax[r] > mst[r] + 8.0f);
    if (__any(need)) {
#pragma unroll
      for (int r = 0; r < 4; ++r) {
        float mnew  = fmaxf(mst[r], rmax[r]);
        float alpha = __expf(mst[r] - mnew);
        mst[r] = mnew;
        lst[r] *= alpha;
#pragma unroll
        for (int nf = 0; nf < 8; ++nf) oacc[nf][r] *= alpha;
      }
    }

    float rsum[4] = {0.f, 0.f, 0.f, 0.f};
#pragma unroll
    for (int n = 0; n < 4; ++n)
#pragma unroll
      for (int r = 0; r < 4; ++r) {
        float pv = __expf(sacc[n][r] - mst[r]);   // bounded by e^8
        rsum[r] += pv;
        Ps[wave][lgrp * 4 + r][n * 16 + lrow] = f2bf(pv);
      }
#pragma unroll
    for (int off = 8; off >= 1; off >>= 1)
#pragma unroll
      for (int r = 0; r < 4; ++r) rsum[r] += __shfl_xor(rsum[r], off, 64);
#pragma unroll
    for (int r = 0; r < 4; ++r) lst[r] += rsum[r];

    // Ps write->read is same-wave cross-lane: wait for LDS writes to land.
    asm volatile("s_waitcnt lgkmcnt(0)" ::: "memory");

    // O += P V : P is 16x64 (per-wave LDS), V via HW-transpose reads.
    __builtin_amdgcn_s_setprio(1);
#pragma unroll
    for (int kk2 = 0; kk2 < 2; ++kk2) {
      u16x8 af = *(const u16x8*)&Ps[wave][lrow][kk2 * 32 + lgrp * 8];
#pragma unroll
      for (int nf = 0; nf < 8; ++nf) {
        const int vbase = nf * 2048 + kk2 * 1024 + lgrp * 256 + lrow * 8;
        u16x4 lo, hi;
        trpair(&Vs[cur][0], vbase, lo, hi);
        u16x8 bfr;
        bfr[0] = lo[0]; bfr[1] = lo[1]; bfr[2] = lo[2]; bfr[3] = lo[3];
        bfr[4] = hi[0]; bfr[5] = hi[1]; bfr[6] = hi[2]; bfr[7] = hi[3];
        oacc[nf] = mfma16(af, bfr, oacc[nf]);
      }
    }
    __builtin_amdgcn_s_setprio(0);

    __builtin_amdgcn_s_barrier();   // all waves done with buf[cur] before restage
  }

  float inv[4];
#pragma unroll
  for (int r = 0; r < 4; ++r) inv[r] = 1.0f / lst[r];
#pragma unroll
  for (int nf = 0; nf < 8; ++nf)
#pragma unroll
    for (int r = 0; r < 4; ++r)
      O[(qrow0 + lgrp * 4 + r) * os + colBase + nf * 16 + lrow] =
          f2bf(oacc[nf][r] * inv[r]);
}

// ---------------- launch ----------------------------------------------------
extern "C" void kernel_launch(void* const* d_in, const int* in_sizes, int n_in,
                              void* d_out, int out_size, void* d_ws, size_t ws_size,
                              hipStream_t stream) {
  const float* x  = (const float*)d_in[0];
  const float* fc = (const float*)d_in[1];
  const float* fs = (const float*)d_in[2];
  const float* wq = (const float*)d_in[3];
  const float* wk = (const float*)d_in[4];
  const float* wv = (const float*)d_in[5];
  const float* wo = (const float*)d_in[6];
  float* out = (float*)d_out;

  // ws layout (bf16 elements), total 58,720,256 elems = 112 MiB.
  uint16_t* w16  = (uint16_t*)d_ws;
  uint16_t* xb   = w16;                   //  8,388,608  x  [4096][2048]
  uint16_t* wqkv = xb + 8388608;          // 12,582,912  [6144][2048] (wq|wk|wv)
  uint16_t* wob  = wqkv + 12582912;       //  4,194,304  [2048][2048]
  uint16_t* qkv  = wob + 4194304;         // 25,165,824  [4096][6144] (q|k|v)
  uint16_t* ob   = qkv + 25165824;        //  8,388,608  [4096][2048]

  // allow 128 KiB dynamic LDS (host-side attribute; not a stream op)
  static int lds_ok = [] {
    (void)hipFuncSetAttribute((const void*)gemm256<0>,
                              hipFuncAttributeMaxDynamicSharedMemorySize, 131072);
    (void)hipFuncSetAttribute((const void*)gemm256<1>,
                              hipFuncAttributeMaxDynamicSharedMemorySize, 131072);
    return 1;
  }();
  (void)lds_ok;

  // casts
  cast_f32_bf16<<<8192, 256, 0, stream>>>(x, xb, 8388608 / 4);
  cast3_f32_bf16<<<3 * 4096, 256, 0, stream>>>(wq, wk, wv, wqkv);
  cast_f32_bf16<<<4096, 256, 0, stream>>>(wo, wob, 4194304 / 4);

  // fused QKV projection: [4096][6144] = xb @ wqkv^T   (384 blocks)
  gemm256<0><<<(QKVS / 256) * (MR / 256), 512, 131072, stream>>>(
      xb, wqkv, nullptr, qkv, MR, QKVS, DIM);

  // RoPE on q,k halves of qkv
  rope_qk<<<(MR * (DIM / 2)) / 256, 256, 0, stream>>>(qkv, fc, fs);

  // attention: Q,K,V strided views into qkv
  dim3 ga(BB * NH, TT / 64);
  attn_fwd<<<ga, 256, 0, stream>>>(qkv, qkv + DIM, qkv + 2 * DIM, ob);

  // output projection -> fp32 d_out   (128 blocks)
  gemm256<1><<<(DIM / 256) * (MR / 256), 512, 131072, stream>>>(
      ob, wob, out, nullptr, MR, DIM, DIM);
}

// Round 6
// 292.601 us; speedup vs baseline: 1.5857x; 1.0283x over previous
//
#include <hip/hip_runtime.h>
#include <stdint.h>

// Problem constants
#define BB 4
#define TT 1024
#define DIM 2048
#define NH 16
#define HD 128
#define MR 4096   // BB*TT rows
#define QKVS (3 * DIM)   // 6144: row stride of fused qkv buffer

typedef __attribute__((ext_vector_type(4))) float    f32x4;
typedef __attribute__((ext_vector_type(8))) uint16_t u16x8;
typedef __attribute__((ext_vector_type(4))) uint16_t u16x4;
typedef __attribute__((ext_vector_type(4))) short    s16x4;
typedef __attribute__((ext_vector_type(8))) __bf16   bf16x8;

static __device__ __forceinline__ uint16_t f2bf(float f) {
  uint32_t u = __builtin_bit_cast(uint32_t, f);
  u += 0x7fffu + ((u >> 16) & 1u);   // round-to-nearest-even
  return (uint16_t)(u >> 16);
}
static __device__ __forceinline__ float bf2f(uint16_t b) {
  uint32_t u = ((uint32_t)b) << 16;
  return __builtin_bit_cast(float, u);
}

static __device__ __forceinline__ f32x4 mfma16(u16x8 a, u16x8 b, f32x4 c) {
  return __builtin_amdgcn_mfma_f32_16x16x32_bf16(
      __builtin_bit_cast(bf16x8, a), __builtin_bit_cast(bf16x8, b), c, 0, 0, 0);
}

// async global->LDS, 16B per lane; LDS dest = wave-uniform base + lane*16
static __device__ __forceinline__ void load_lds_16B(const void* g, void* l) {
  __builtin_amdgcn_global_load_lds(
      (const __attribute__((address_space(1))) void*)g,
      (__attribute__((address_space(3))) void*)l, 16, 0, 0);
}

// paired hardware transpose reads at byteoff and byteoff+128.
static __device__ __forceinline__ void trpair(const uint16_t* base, int byteoff,
                                              u16x4& lo, u16x4& hi) {
  __attribute__((address_space(3))) char* ap =
      (__attribute__((address_space(3))) char*)(void*)base + byteoff;
#if defined(__has_builtin) && __has_builtin(__builtin_amdgcn_ds_read_tr16_b64_v4i16)
  s16x4 r0 = __builtin_amdgcn_ds_read_tr16_b64_v4i16(
      (__attribute__((address_space(3))) s16x4*)ap);
  s16x4 r1 = __builtin_amdgcn_ds_read_tr16_b64_v4i16(
      (__attribute__((address_space(3))) s16x4*)(ap + 128));
  lo = __builtin_bit_cast(u16x4, r0);
  hi = __builtin_bit_cast(u16x4, r1);
#else
  uint32_t a32 = (uint32_t)(uintptr_t)ap;
  asm volatile("ds_read_b64_tr_b16 %0, %2\n\t"
               "ds_read_b64_tr_b16 %1, %2 offset:128\n\t"
               "s_waitcnt lgkmcnt(0)"
               : "=&v"(lo), "=&v"(hi) : "v"(a32));
#endif
}

// ---------------- casts fp32 -> bf16 (vectorized) ----------------
__global__ __launch_bounds__(256) void cast_f32_bf16(const float* __restrict__ in,
                                                     uint16_t* __restrict__ out, int n4) {
  int i = blockIdx.x * 256 + threadIdx.x;
  if (i >= n4) return;
  f32x4 v = ((const f32x4*)in)[i];
  u16x4 o;
  o[0] = f2bf(v[0]); o[1] = f2bf(v[1]); o[2] = f2bf(v[2]); o[3] = f2bf(v[3]);
  ((u16x4*)out)[i] = o;
}

// three equal-size sources -> one contiguous dest (wq|wk|wv)
__global__ __launch_bounds__(256) void cast3_f32_bf16(const float* __restrict__ s0,
                                                      const float* __restrict__ s1,
                                                      const float* __restrict__ s2,
                                                      uint16_t* __restrict__ out) {
  const int per = 4194304 / 4;   // f32x4 chunks per matrix
  int i = blockIdx.x * 256 + threadIdx.x;          // [0, 3*per)
  const float* src = (i < per) ? s0 : (i < 2 * per) ? s1 : s2;
  int j = (i < per) ? i : (i < 2 * per) ? (i - per) : (i - 2 * per);
  f32x4 v = ((const f32x4*)src)[j];
  u16x4 o;
  o[0] = f2bf(v[0]); o[1] = f2bf(v[1]); o[2] = f2bf(v[2]); o[3] = f2bf(v[3]);
  ((u16x4*)out)[i] = o;
}

// ---------------- GEMM 128x128, BK=32, quad-buffered -------------------------
// C[M,N] = A[M,K] * Bt[N,K]^T (bf16 row-major). 256 thr = 4 waves (2x2),
// per-wave 64x64 = 4x4 16x16 frags. LDS: 4 bufs x (A 8KB + B 8KB) = 64 KiB
// -> 2 blocks/CU. Stage tile t+3 while computing t (targets buf (t-1)&3,
// whose readers are behind this iteration's barrier -> race-free with ONE
// barrier + counted vmcnt(8) per K-tile; vmcnt never drains mid-loop).
// Swizzle: stored chunk = c ^ ((row>>1)&3) (16B chunks, 4/row) applied on the
// global source (linear LDS dest) and on the ds_read address.
// MODE: 1 = f32 out, 2 = bf16 out + fused RoPE on cols [0, 2*DIM).
template <int MODE>
__global__ __launch_bounds__(256, 2) void gemm128(const uint16_t* __restrict__ A,
                                                  const uint16_t* __restrict__ Bt,
                                                  float* __restrict__ Cf,
                                                  uint16_t* __restrict__ Cb,
                                                  const float* __restrict__ cosT,
                                                  const float* __restrict__ sinT,
                                                  int M, int N, int K) {
  extern __shared__ __attribute__((aligned(16))) uint16_t smem[];  // 65536 B
  const int tid  = threadIdx.x;
  const int lane = tid & 63;
  const int wave = tid >> 6;
  const int lrow = lane & 15;
  const int lgrp = lane >> 4;
  const int wr   = (wave >> 1) * 64;
  const int wc   = (wave & 1) * 64;

  // T1: XCD-aware block swizzle (grids are multiples of 8)
  const int nbx = N >> 7, nby = M >> 7;
  const int nwg = nbx * nby;
  const int wg  = ((int)blockIdx.x & 7) * (nwg >> 3) + ((int)blockIdx.x >> 3);
  const long bRow = (long)(wg / nbx) << 7;
  const long bCol = (long)(wg % nbx) << 7;

  const f32x4 fz = {0.f, 0.f, 0.f, 0.f};
  f32x4 acc[4][4];
#pragma unroll
  for (int m = 0; m < 4; ++m)
#pragma unroll
    for (int n = 0; n < 4; ++n) acc[m][n] = fz;

  auto stage = [&](int kt, int buf) {
    const long kb = (long)kt << 5;
    char* base = (char*)smem + buf * 16384;
#pragma unroll
    for (int i = 0; i < 2; ++i) {
      const int L   = (i * 256 + tid) * 16;
      const int row = L >> 6;                           // 0..127
      const int c   = ((L >> 4) & 3) ^ ((row >> 1) & 3);
      load_lds_16B(A + (bRow + row) * (long)K + kb + c * 8, base + L);
    }
#pragma unroll
    for (int i = 0; i < 2; ++i) {
      const int L   = (i * 256 + tid) * 16;
      const int row = L >> 6;
      const int c   = ((L >> 4) & 3) ^ ((row >> 1) & 3);
      load_lds_16B(Bt + (bCol + row) * (long)K + kb + c * 8, base + 8192 + L);
    }
  };

  const int NT = K >> 5;   // 64 K-tiles
  stage(0, 0); stage(1, 1); stage(2, 2);   // 12 loads in flight

  for (int t = 0; t < NT; ++t) {
    const int cur = t & 3;
    if (t < NT - 2)       asm volatile("s_waitcnt vmcnt(8)" ::: "memory");
    else if (t == NT - 2) asm volatile("s_waitcnt vmcnt(4)" ::: "memory");
    else                  asm volatile("s_waitcnt vmcnt(0)" ::: "memory");
    __builtin_amdgcn_s_barrier();          // tile t landed; buf (t-1)&3 free
    if (t + 3 < NT) stage(t + 3, (t + 3) & 3);

    const char* Ab = (const char*)smem + cur * 16384;
    const char* Bb = Ab + 8192;
    u16x8 af[4], bf[4];
#pragma unroll
    for (int m = 0; m < 4; ++m) {
      const int row = wr + m * 16 + lrow;
      af[m] = *(const u16x8*)(Ab + row * 64 + (lgrp ^ ((row >> 1) & 3)) * 16);
    }
#pragma unroll
    for (int n = 0; n < 4; ++n) {
      const int row = wc + n * 16 + lrow;
      bf[n] = *(const u16x8*)(Bb + row * 64 + (lgrp ^ ((row >> 1) & 3)) * 16);
    }
    __builtin_amdgcn_s_setprio(1);
#pragma unroll
    for (int m = 0; m < 4; ++m)
#pragma unroll
      for (int n = 0; n < 4; ++n) acc[m][n] = mfma16(af[m], bf[n], acc[m][n]);
    __builtin_amdgcn_s_setprio(0);
  }

  // epilogue (optionally fused RoPE on q/k column range)
  const bool doRope = (MODE == 2) && (bCol < 2 * DIM);
#pragma unroll
  for (int m = 0; m < 4; ++m)
#pragma unroll
    for (int n = 0; n < 4; ++n) {
      const long grow0 = bRow + wr + m * 16 + lgrp * 4;
      const long gcol  = bCol + wc + n * 16 + lrow;
      if (doRope) {
        const int  fi  = ((int)gcol >> 1) & 63;
        const bool odd = (gcol & 1) != 0;
#pragma unroll
        for (int r = 0; r < 4; ++r) {
          const long grow = grow0 + r;
          const int  tt   = (int)grow & (TT - 1);
          float v = acc[m][n][r];
          float p = __shfl_xor(v, 1, 64);   // partner column (lane^1)
          float cc = cosT[tt * 64 + fi];
          float ss = sinT[tt * 64 + fi];
          float o  = odd ? (p * ss + v * cc) : (v * cc - p * ss);
          Cb[grow * (long)N + gcol] = f2bf(o);
        }
      } else {
#pragma unroll
        for (int r = 0; r < 4; ++r) {
          const long idx = (grow0 + r) * (long)N + gcol;
          if (MODE == 1) Cf[idx] = acc[m][n][r];
          else           Cb[idx] = f2bf(acc[m][n][r]);
        }
      }
    }
}

// ---------------- Flash attention fwd ---------------------------------------
// grid (BB*NH, TT/64). 256 threads = 4 waves; each wave owns 16 q-rows.
// Counted-vmcnt double-buffered K/V staging; raw barriers; K XOR-swizzled;
// V subtiled for ds_read_b64_tr_b16; defer-max (T13).
__global__ __launch_bounds__(256) void attn_fwd(const uint16_t* __restrict__ Q,
                                                const uint16_t* __restrict__ K,
                                                const uint16_t* __restrict__ V,
                                                uint16_t* __restrict__ O) {
  __shared__ __attribute__((aligned(16))) uint16_t Ks[2][64 * 128];  // 2x16 KB
  __shared__ __attribute__((aligned(16))) uint16_t Vs[2][64 * 128];  // 2x16 KB
  __shared__ __attribute__((aligned(16))) uint16_t Ps[4][16][72];    // 9 KB
  const int tid  = threadIdx.x;
  const int lane = tid & 63;
  const int wave = tid >> 6;
  const int lrow = lane & 15;
  const int lgrp = lane >> 4;
  const int b  = blockIdx.x >> 4;
  const int h  = blockIdx.x & 15;
  const int qt = blockIdx.y;
  const long colBase = (long)h * HD;
  const long rs = QKVS;      // q/k/v row stride (fused buffer)
  const long os = DIM;       // output row stride
  const long qrow0 = (long)b * TT + qt * 64 + wave * 16;

  u16x8 qf[4];
#pragma unroll
  for (int kkk = 0; kkk < 4; ++kkk)
    qf[kkk] = *(const u16x8*)(Q + (qrow0 + lrow) * rs + colBase + kkk * 32 + lgrp * 8);

  const f32x4 fz = {0.f, 0.f, 0.f, 0.f};
  f32x4 oacc[8];
#pragma unroll
  for (int nf = 0; nf < 8; ++nf) oacc[nf] = fz;
  float mst[4] = {-1e30f, -1e30f, -1e30f, -1e30f};
  float lst[4] = {0.f, 0.f, 0.f, 0.f};
  const float scale = 0.08838834764831845f;  // 1/sqrt(128)

  auto stage = [&](int kt, int buf) {
    const long krow = (long)b * TT + kt * 64;
#pragma unroll
    for (int i = 0; i < 4; ++i) {
      const int L = (i * 256 + tid) * 16;   // buf-relative linear byte position
      const int krw = L >> 8;
      const int ksc = ((L >> 4) & 15) ^ (krw & 7);
      load_lds_16B(K + (krow + krw) * rs + colBase + ksc * 8,
                   (char*)&Ks[buf][0] + L);
      const int vbl = L >> 11;
      const int vkv = ((L >> 7) & 15) * 4 + ((L >> 5) & 3);
      const int vd  = vbl * 16 + ((L >> 4) & 1) * 8;
      load_lds_16B(V + (krow + vkv) * rs + colBase + vd,
                   (char*)&Vs[buf][0] + L);
    }
  };

  stage(0, 0);   // prologue: 8 loads in flight

  for (int kt2 = 0; kt2 < TT / 64; ++kt2) {
    const int cur = kt2 & 1;
    if (kt2 < TT / 64 - 1) {
      stage(kt2 + 1, cur ^ 1);                          // 8 more in flight
      asm volatile("s_waitcnt vmcnt(8)" ::: "memory");  // tile kt2's loads done
    } else {
      asm volatile("s_waitcnt vmcnt(0)" ::: "memory");
    }
    __builtin_amdgcn_s_barrier();   // raw: no compiler vmcnt(0) drain

    // S = Q K^T : 16x64 per wave
    f32x4 sacc[4];
#pragma unroll
    for (int n = 0; n < 4; ++n) sacc[n] = fz;
    __builtin_amdgcn_s_setprio(1);
#pragma unroll
    for (int kkk = 0; kkk < 4; ++kkk) {
#pragma unroll
      for (int n = 0; n < 4; ++n) {
        const int row = n * 16 + lrow;
        const int ch  = (kkk * 4 + lgrp) ^ (row & 7);
        u16x8 bfr = *(const u16x8*)((const char*)&Ks[cur][0] + row * 256 + ch * 16);
        sacc[n] = mfma16(qf[kkk], bfr, sacc[n]);
      }
    }
    __builtin_amdgcn_s_setprio(0);
#pragma unroll
    for (int n = 0; n < 4; ++n) sacc[n] *= scale;

    // row max over 64 cols: 4 frags then 16-lane butterfly
    float rmax[4];
#pragma unroll
    for (int r = 0; r < 4; ++r)
      rmax[r] = fmaxf(fmaxf(sacc[0][r], sacc[1][r]), fmaxf(sacc[2][r], sacc[3][r]));
#pragma unroll
    for (int off = 8; off >= 1; off >>= 1)
#pragma unroll
      for (int r = 0; r < 4; ++r)
        rmax[r] = fmaxf(rmax[r], __shfl_xor(rmax[r], off, 64));

    // defer-max (T13): rescale only when max grew past threshold
    bool need = false;
#pragma unroll
    for (int r = 0; r < 4; ++r) need = need || (rmax[r] > mst[r] + 8.0f);
    if (__any(need)) {
#pragma unroll
      for (int r = 0; r < 4; ++r) {
        float mnew  = fmaxf(mst[r], rmax[r]);
        float alpha = __expf(mst[r] - mnew);
        mst[r] = mnew;
        lst[r] *= alpha;
#pragma unroll
        for (int nf = 0; nf < 8; ++nf) oacc[nf][r] *= alpha;
      }
    }

    float rsum[4] = {0.f, 0.f, 0.f, 0.f};
#pragma unroll
    for (int n = 0; n < 4; ++n)
#pragma unroll
      for (int r = 0; r < 4; ++r) {
        float pv = __expf(sacc[n][r] - mst[r]);   // bounded by e^8
        rsum[r] += pv;
        Ps[wave][lgrp * 4 + r][n * 16 + lrow] = f2bf(pv);
      }
#pragma unroll
    for (int off = 8; off >= 1; off >>= 1)
#pragma unroll
      for (int r = 0; r < 4; ++r) rsum[r] += __shfl_xor(rsum[r], off, 64);
#pragma unroll
    for (int r = 0; r < 4; ++r) lst[r] += rsum[r];

    // Ps write->read is same-wave cross-lane: wait for LDS writes to land.
    asm volatile("s_waitcnt lgkmcnt(0)" ::: "memory");

    // O += P V : P is 16x64 (per-wave LDS), V via HW-transpose reads.
    __builtin_amdgcn_s_setprio(1);
#pragma unroll
    for (int kk2 = 0; kk2 < 2; ++kk2) {
      u16x8 af = *(const u16x8*)&Ps[wave][lrow][kk2 * 32 + lgrp * 8];
#pragma unroll
      for (int nf = 0; nf < 8; ++nf) {
        const int vbase = nf * 2048 + kk2 * 1024 + lgrp * 256 + lrow * 8;
        u16x4 lo, hi;
        trpair(&Vs[cur][0], vbase, lo, hi);
        u16x8 bfr;
        bfr[0] = lo[0]; bfr[1] = lo[1]; bfr[2] = lo[2]; bfr[3] = lo[3];
        bfr[4] = hi[0]; bfr[5] = hi[1]; bfr[6] = hi[2]; bfr[7] = hi[3];
        oacc[nf] = mfma16(af, bfr, oacc[nf]);
      }
    }
    __builtin_amdgcn_s_setprio(0);

    __builtin_amdgcn_s_barrier();   // all waves done with buf[cur] before restage
  }

  float inv[4];
#pragma unroll
  for (int r = 0; r < 4; ++r) inv[r] = 1.0f / lst[r];
#pragma unroll
  for (int nf = 0; nf < 8; ++nf)
#pragma unroll
    for (int r = 0; r < 4; ++r)
      O[(qrow0 + lgrp * 4 + r) * os + colBase + nf * 16 + lrow] =
          f2bf(oacc[nf][r] * inv[r]);
}

// ---------------- launch ----------------------------------------------------
extern "C" void kernel_launch(void* const* d_in, const int* in_sizes, int n_in,
                              void* d_out, int out_size, void* d_ws, size_t ws_size,
                              hipStream_t stream) {
  const float* x  = (const float*)d_in[0];
  const float* fc = (const float*)d_in[1];
  const float* fs = (const float*)d_in[2];
  const float* wq = (const float*)d_in[3];
  const float* wk = (const float*)d_in[4];
  const float* wv = (const float*)d_in[5];
  const float* wo = (const float*)d_in[6];
  float* out = (float*)d_out;

  // ws layout (bf16 elements), total 58,720,256 elems = 112 MiB.
  uint16_t* w16  = (uint16_t*)d_ws;
  uint16_t* xb   = w16;                   //  8,388,608  x  [4096][2048]
  uint16_t* wqkv = xb + 8388608;          // 12,582,912  [6144][2048] (wq|wk|wv)
  uint16_t* wob  = wqkv + 12582912;       //  4,194,304  [2048][2048]
  uint16_t* qkv  = wob + 4194304;         // 25,165,824  [4096][6144] (q|k|v)
  uint16_t* ob   = qkv + 25165824;        //  8,388,608  [4096][2048]

  static int lds_ok = [] {
    (void)hipFuncSetAttribute((const void*)gemm128<1>,
                              hipFuncAttributeMaxDynamicSharedMemorySize, 65536);
    (void)hipFuncSetAttribute((const void*)gemm128<2>,
                              hipFuncAttributeMaxDynamicSharedMemorySize, 65536);
    return 1;
  }();
  (void)lds_ok;

  // casts
  cast_f32_bf16<<<8192, 256, 0, stream>>>(x, xb, 8388608 / 4);
  cast3_f32_bf16<<<3 * 4096, 256, 0, stream>>>(wq, wk, wv, wqkv);
  cast_f32_bf16<<<4096, 256, 0, stream>>>(wo, wob, 4194304 / 4);

  // fused QKV projection + RoPE epilogue: [4096][6144] = xb @ wqkv^T
  gemm128<2><<<(MR / 128) * (QKVS / 128), 256, 65536, stream>>>(
      xb, wqkv, nullptr, qkv, fc, fs, MR, QKVS, DIM);

  // attention: Q,K,V strided views into qkv
  dim3 ga(BB * NH, TT / 64);
  attn_fwd<<<ga, 256, 0, stream>>>(qkv, qkv + DIM, qkv + 2 * DIM, ob);

  // output projection -> fp32 d_out
  gemm128<1><<<(MR / 128) * (DIM / 128), 256, 65536, stream>>>(
      ob, wob, out, nullptr, nullptr, nullptr, MR, DIM, DIM);
}

// Round 7
// 280.916 us; speedup vs baseline: 1.6516x; 1.0416x over previous
//
#include <hip/hip_runtime.h>
#include <stdint.h>

// Problem constants
#define BB 4
#define TT 1024
#define DIM 2048
#define NH 16
#define HD 128
#define MR 4096   // BB*TT rows
#define QKVS (3 * DIM)   // 6144: row stride of fused qkv buffer

typedef __attribute__((ext_vector_type(4))) float    f32x4;
typedef __attribute__((ext_vector_type(8))) uint16_t u16x8;
typedef __attribute__((ext_vector_type(4))) uint16_t u16x4;
typedef __attribute__((ext_vector_type(4))) short    s16x4;
typedef __attribute__((ext_vector_type(8))) __bf16   bf16x8;

static __device__ __forceinline__ uint16_t f2bf(float f) {
  uint32_t u = __builtin_bit_cast(uint32_t, f);
  u += 0x7fffu + ((u >> 16) & 1u);   // round-to-nearest-even
  return (uint16_t)(u >> 16);
}
static __device__ __forceinline__ float bf2f(uint16_t b) {
  uint32_t u = ((uint32_t)b) << 16;
  return __builtin_bit_cast(float, u);
}

static __device__ __forceinline__ f32x4 mfma16(u16x8 a, u16x8 b, f32x4 c) {
  return __builtin_amdgcn_mfma_f32_16x16x32_bf16(
      __builtin_bit_cast(bf16x8, a), __builtin_bit_cast(bf16x8, b), c, 0, 0, 0);
}

// async global->LDS, 16B per lane; LDS dest = wave-uniform base + lane*16
static __device__ __forceinline__ void load_lds_16B(const void* g, void* l) {
  __builtin_amdgcn_global_load_lds(
      (const __attribute__((address_space(1))) void*)g,
      (__attribute__((address_space(3))) void*)l, 16, 0, 0);
}

// paired hardware transpose reads at byteoff and byteoff+128.
static __device__ __forceinline__ void trpair(const uint16_t* base, int byteoff,
                                              u16x4& lo, u16x4& hi) {
  __attribute__((address_space(3))) char* ap =
      (__attribute__((address_space(3))) char*)(void*)base + byteoff;
#if defined(__has_builtin) && __has_builtin(__builtin_amdgcn_ds_read_tr16_b64_v4i16)
  s16x4 r0 = __builtin_amdgcn_ds_read_tr16_b64_v4i16(
      (__attribute__((address_space(3))) s16x4*)ap);
  s16x4 r1 = __builtin_amdgcn_ds_read_tr16_b64_v4i16(
      (__attribute__((address_space(3))) s16x4*)(ap + 128));
  lo = __builtin_bit_cast(u16x4, r0);
  hi = __builtin_bit_cast(u16x4, r1);
#else
  uint32_t a32 = (uint32_t)(uintptr_t)ap;
  asm volatile("ds_read_b64_tr_b16 %0, %2\n\t"
               "ds_read_b64_tr_b16 %1, %2 offset:128\n\t"
               "s_waitcnt lgkmcnt(0)"
               : "=&v"(lo), "=&v"(hi) : "v"(a32));
#endif
}

// ---------------- casts fp32 -> bf16 (vectorized) ----------------
__global__ __launch_bounds__(256) void cast_f32_bf16(const float* __restrict__ in,
                                                     uint16_t* __restrict__ out, int n4) {
  int i = blockIdx.x * 256 + threadIdx.x;
  if (i >= n4) return;
  f32x4 v = ((const f32x4*)in)[i];
  u16x4 o;
  o[0] = f2bf(v[0]); o[1] = f2bf(v[1]); o[2] = f2bf(v[2]); o[3] = f2bf(v[3]);
  ((u16x4*)out)[i] = o;
}

// three equal-size sources -> one contiguous dest (wq|wk|wv)
__global__ __launch_bounds__(256) void cast3_f32_bf16(const float* __restrict__ s0,
                                                      const float* __restrict__ s1,
                                                      const float* __restrict__ s2,
                                                      uint16_t* __restrict__ out) {
  const int per = 4194304 / 4;   // f32x4 chunks per matrix
  int i = blockIdx.x * 256 + threadIdx.x;          // [0, 3*per)
  const float* src = (i < per) ? s0 : (i < 2 * per) ? s1 : s2;
  int j = (i < per) ? i : (i < 2 * per) ? (i - per) : (i - 2 * per);
  f32x4 v = ((const f32x4*)src)[j];
  u16x4 o;
  o[0] = f2bf(v[0]); o[1] = f2bf(v[1]); o[2] = f2bf(v[2]); o[3] = f2bf(v[3]);
  ((u16x4*)out)[i] = o;
}

// ---------------- GEMM 256x256, BK=64, 8-wave 4-phase (m201-style) -----------
// C[M,N] = A[M,K] * Bt[N,K]^T (bf16 row-major). 512 thr = 8 waves (2M x 4N);
// per-wave C = 128x64 = 8x4 16x16 frags (0.375 LDS reads/MFMA). LDS 128 KiB:
// 2 bufs x (A 256x64 = 32 KB + B 32 KB), XOR-swizzled chunks (ch ^ (row&7))
// via pre-swizzled global source (linear gload_lds dest).
// Per K-tile: 4 phases (mh,kk); each phase: [stage half-tiles (ph0: A of T+1,
// ph1: B of T+1)] -> 8 ds_read_b128 -> barrier -> 16 MFMA -> barrier.
// Boundary vmcnt(0) at ph3 (loads had 2.5-4 phase lead). Raw barriers.
// MODE: 0 = bf16 out, 2 = bf16 out + fused RoPE on cols [0, 2*DIM).
template <int MODE>
__global__ __launch_bounds__(512, 2) void gemm256_8ph(const uint16_t* __restrict__ A,
                                                      const uint16_t* __restrict__ Bt,
                                                      uint16_t* __restrict__ Cb,
                                                      const float* __restrict__ cosT,
                                                      const float* __restrict__ sinT,
                                                      int M, int N, int K) {
  extern __shared__ __attribute__((aligned(16))) uint16_t smem[];  // 131072 B
  const int tid  = threadIdx.x;
  const int lane = tid & 63;
  const int wave = tid >> 6;          // 0..7
  const int lrow = lane & 15;
  const int lgrp = lane >> 4;
  const int wr   = (wave >> 2) * 128; // 0 / 128
  const int wc   = (wave & 3) * 64;   // 0,64,128,192

  // T1: XCD-aware block swizzle (grid % 8 == 0)
  const int nbx = N >> 8, nby = M >> 8;
  const int nwg = nbx * nby;
  const int wg  = ((int)blockIdx.x & 7) * (nwg >> 3) + ((int)blockIdx.x >> 3);
  const long bRow = (long)(wg / nbx) << 8;
  const long bCol = (long)(wg % nbx) << 8;

  const f32x4 fz = {0.f, 0.f, 0.f, 0.f};
  f32x4 acc[8][4];
#pragma unroll
  for (int m = 0; m < 8; ++m)
#pragma unroll
    for (int n = 0; n < 4; ++n) acc[m][n] = fz;

  // stage one 16 KB half-tile (128 rows x 64 cols): 2 gload_lds per thread.
  // LDS[row][c'] = G[row][c' ^ (row&7)], 16B chunks, 8/row.
  auto stageA = [&](int kt, int buf, int half) {
    const long kb = (long)kt << 6;
    char* dst = (char*)smem + buf * 65536 + half * 16384;
#pragma unroll
    for (int i = 0; i < 2; ++i) {
      const int L   = (i * 512 + tid) * 16;
      const int row = (L >> 7) + half * 128;
      const int ch  = ((L >> 4) & 7) ^ (row & 7);
      load_lds_16B(A + (bRow + row) * (long)K + kb + ch * 8, dst + L);
    }
  };
  auto stageB = [&](int kt, int buf, int half) {
    const long kb = (long)kt << 6;
    char* dst = (char*)smem + buf * 65536 + 32768 + half * 16384;
#pragma unroll
    for (int i = 0; i < 2; ++i) {
      const int L   = (i * 512 + tid) * 16;
      const int row = (L >> 7) + half * 128;
      const int ch  = ((L >> 4) & 7) ^ (row & 7);
      load_lds_16B(Bt + (bCol + row) * (long)K + kb + ch * 8, dst + L);
    }
  };

  const int NT = K >> 6;   // 32 K-tiles

  // prologue: tile 0 -> buf 0
  stageA(0, 0, 0); stageA(0, 0, 1); stageB(0, 0, 0); stageB(0, 0, 1);
  asm volatile("s_waitcnt vmcnt(0)" ::: "memory");
  __builtin_amdgcn_s_barrier();

#define PHASE(MH, KK, LAST)                                                  \
  {                                                                          \
    u16x8 af_[4], bf_[4];                                                    \
    _Pragma("unroll")                                                        \
    for (int j = 0; j < 4; ++j) {                                            \
      const int row = wr + ((MH) * 4 + j) * 16 + lrow;                       \
      const int ch  = ((KK) * 4 + lgrp) ^ (row & 7);                         \
      af_[j] = *(const u16x8*)(Ab + row * 128 + ch * 16);                    \
    }                                                                        \
    _Pragma("unroll")                                                        \
    for (int n = 0; n < 4; ++n) {                                            \
      const int row = wc + n * 16 + lrow;                                    \
      const int ch  = ((KK) * 4 + lgrp) ^ (row & 7);                         \
      bf_[n] = *(const u16x8*)(Bb + row * 128 + ch * 16);                    \
    }                                                                        \
    __builtin_amdgcn_s_barrier();                                            \
    __builtin_amdgcn_s_setprio(1);                                           \
    _Pragma("unroll")                                                        \
    for (int j = 0; j < 4; ++j)                                              \
      _Pragma("unroll")                                                      \
      for (int n = 0; n < 4; ++n)                                            \
        acc[(MH) * 4 + j][n] = mfma16(af_[j], bf_[n], acc[(MH) * 4 + j][n]); \
    __builtin_amdgcn_s_setprio(0);                                           \
    if (LAST) asm volatile("s_waitcnt vmcnt(0)" ::: "memory");               \
    __builtin_amdgcn_s_barrier();                                            \
  }

  for (int T = 0; T < NT; ++T) {
    const int cb = T & 1;
    const char* Ab = (const char*)smem + cb * 65536;
    const char* Bb = Ab + 32768;
    const int nb = cb ^ 1;
    // ph0: stage next tile's A halves (other buf; vacated at T-1's ph3)
    if (T + 1 < NT) { stageA(T + 1, nb, 0); stageA(T + 1, nb, 1); }
    PHASE(0, 0, 0)
    // ph1: stage next tile's B halves
    if (T + 1 < NT) { stageB(T + 1, nb, 0); stageB(T + 1, nb, 1); }
    PHASE(0, 1, 0)
    PHASE(1, 0, 0)
    PHASE(1, 1, 1)   // boundary: vmcnt(0) then barrier -> next tile staged
  }
#undef PHASE

  // epilogue (MODE 2: fused RoPE on q/k column range)
  const bool doRope = (MODE == 2) && (bCol < 2 * DIM);
#pragma unroll
  for (int m = 0; m < 8; ++m)
#pragma unroll
    for (int n = 0; n < 4; ++n) {
      const long grow0 = bRow + wr + m * 16 + lgrp * 4;
      const long gcol  = bCol + wc + n * 16 + lrow;
      if (doRope) {
        const int  fi  = ((int)gcol >> 1) & 63;
        const bool odd = (gcol & 1) != 0;
#pragma unroll
        for (int r = 0; r < 4; ++r) {
          const long grow = grow0 + r;
          const int  ttt  = (int)grow & (TT - 1);
          float v = acc[m][n][r];
          float p = __shfl_xor(v, 1, 64);   // partner column (lane^1)
          float cc = cosT[ttt * 64 + fi];
          float ss = sinT[ttt * 64 + fi];
          float o  = odd ? (p * ss + v * cc) : (v * cc - p * ss);
          Cb[grow * (long)N + gcol] = f2bf(o);
        }
      } else {
#pragma unroll
        for (int r = 0; r < 4; ++r)
          Cb[(grow0 + r) * (long)N + gcol] = f2bf(acc[m][n][r]);
      }
    }
}

// ---------------- GEMM 128x128, BK=32, quad-buffered (out-proj) --------------
template <int MODE>   // 1 = f32 out
__global__ __launch_bounds__(256, 2) void gemm128(const uint16_t* __restrict__ A,
                                                  const uint16_t* __restrict__ Bt,
                                                  float* __restrict__ Cf,
                                                  uint16_t* __restrict__ Cb,
                                                  int M, int N, int K) {
  extern __shared__ __attribute__((aligned(16))) uint16_t smem[];  // 65536 B
  const int tid  = threadIdx.x;
  const int lane = tid & 63;
  const int wave = tid >> 6;
  const int lrow = lane & 15;
  const int lgrp = lane >> 4;
  const int wr   = (wave >> 1) * 64;
  const int wc   = (wave & 1) * 64;

  const int nbx = N >> 7, nby = M >> 7;
  const int nwg = nbx * nby;
  const int wg  = ((int)blockIdx.x & 7) * (nwg >> 3) + ((int)blockIdx.x >> 3);
  const long bRow = (long)(wg / nbx) << 7;
  const long bCol = (long)(wg % nbx) << 7;

  const f32x4 fz = {0.f, 0.f, 0.f, 0.f};
  f32x4 acc[4][4];
#pragma unroll
  for (int m = 0; m < 4; ++m)
#pragma unroll
    for (int n = 0; n < 4; ++n) acc[m][n] = fz;

  auto stage = [&](int kt, int buf) {
    const long kb = (long)kt << 5;
    char* base = (char*)smem + buf * 16384;
#pragma unroll
    for (int i = 0; i < 2; ++i) {
      const int L   = (i * 256 + tid) * 16;
      const int row = L >> 6;
      const int c   = ((L >> 4) & 3) ^ ((row >> 1) & 3);
      load_lds_16B(A + (bRow + row) * (long)K + kb + c * 8, base + L);
    }
#pragma unroll
    for (int i = 0; i < 2; ++i) {
      const int L   = (i * 256 + tid) * 16;
      const int row = L >> 6;
      const int c   = ((L >> 4) & 3) ^ ((row >> 1) & 3);
      load_lds_16B(Bt + (bCol + row) * (long)K + kb + c * 8, base + 8192 + L);
    }
  };

  const int NT = K >> 5;
  stage(0, 0); stage(1, 1); stage(2, 2);

  for (int t = 0; t < NT; ++t) {
    const int cur = t & 3;
    if (t < NT - 2)       asm volatile("s_waitcnt vmcnt(8)" ::: "memory");
    else if (t == NT - 2) asm volatile("s_waitcnt vmcnt(4)" ::: "memory");
    else                  asm volatile("s_waitcnt vmcnt(0)" ::: "memory");
    __builtin_amdgcn_s_barrier();
    if (t + 3 < NT) stage(t + 3, (t + 3) & 3);

    const char* Ab = (const char*)smem + cur * 16384;
    const char* Bb = Ab + 8192;
    u16x8 af[4], bf[4];
#pragma unroll
    for (int m = 0; m < 4; ++m) {
      const int row = wr + m * 16 + lrow;
      af[m] = *(const u16x8*)(Ab + row * 64 + (lgrp ^ ((row >> 1) & 3)) * 16);
    }
#pragma unroll
    for (int n = 0; n < 4; ++n) {
      const int row = wc + n * 16 + lrow;
      bf[n] = *(const u16x8*)(Bb + row * 64 + (lgrp ^ ((row >> 1) & 3)) * 16);
    }
    __builtin_amdgcn_s_setprio(1);
#pragma unroll
    for (int m = 0; m < 4; ++m)
#pragma unroll
      for (int n = 0; n < 4; ++n) acc[m][n] = mfma16(af[m], bf[n], acc[m][n]);
    __builtin_amdgcn_s_setprio(0);
  }

#pragma unroll
  for (int m = 0; m < 4; ++m)
#pragma unroll
    for (int n = 0; n < 4; ++n) {
      const long grow0 = bRow + wr + m * 16 + lgrp * 4;
      const long gcol  = bCol + wc + n * 16 + lrow;
#pragma unroll
      for (int r = 0; r < 4; ++r) {
        const long idx = (grow0 + r) * (long)N + gcol;
        if (MODE == 1) Cf[idx] = acc[m][n][r];
        else           Cb[idx] = f2bf(acc[m][n][r]);
      }
    }
}

// ---------------- Flash attention fwd ---------------------------------------
__global__ __launch_bounds__(256) void attn_fwd(const uint16_t* __restrict__ Q,
                                                const uint16_t* __restrict__ K,
                                                const uint16_t* __restrict__ V,
                                                uint16_t* __restrict__ O) {
  __shared__ __attribute__((aligned(16))) uint16_t Ks[2][64 * 128];
  __shared__ __attribute__((aligned(16))) uint16_t Vs[2][64 * 128];
  __shared__ __attribute__((aligned(16))) uint16_t Ps[4][16][72];
  const int tid  = threadIdx.x;
  const int lane = tid & 63;
  const int wave = tid >> 6;
  const int lrow = lane & 15;
  const int lgrp = lane >> 4;
  const int b  = blockIdx.x >> 4;
  const int h  = blockIdx.x & 15;
  const int qt = blockIdx.y;
  const long colBase = (long)h * HD;
  const long rs = QKVS;
  const long os = DIM;
  const long qrow0 = (long)b * TT + qt * 64 + wave * 16;

  u16x8 qf[4];
#pragma unroll
  for (int kkk = 0; kkk < 4; ++kkk)
    qf[kkk] = *(const u16x8*)(Q + (qrow0 + lrow) * rs + colBase + kkk * 32 + lgrp * 8);

  const f32x4 fz = {0.f, 0.f, 0.f, 0.f};
  f32x4 oacc[8];
#pragma unroll
  for (int nf = 0; nf < 8; ++nf) oacc[nf] = fz;
  float mst[4] = {-1e30f, -1e30f, -1e30f, -1e30f};
  float lst[4] = {0.f, 0.f, 0.f, 0.f};
  const float scale = 0.08838834764831845f;

  auto stage = [&](int kt, int buf) {
    const long krow = (long)b * TT + kt * 64;
#pragma unroll
    for (int i = 0; i < 4; ++i) {
      const int L = (i * 256 + tid) * 16;
      const int krw = L >> 8;
      const int ksc = ((L >> 4) & 15) ^ (krw & 7);
      load_lds_16B(K + (krow + krw) * rs + colBase + ksc * 8,
                   (char*)&Ks[buf][0] + L);
      const int vbl = L >> 11;
      const int vkv = ((L >> 7) & 15) * 4 + ((L >> 5) & 3);
      const int vd  = vbl * 16 + ((L >> 4) & 1) * 8;
      load_lds_16B(V + (krow + vkv) * rs + colBase + vd,
                   (char*)&Vs[buf][0] + L);
    }
  };

  stage(0, 0);

  for (int kt2 = 0; kt2 < TT / 64; ++kt2) {
    const int cur = kt2 & 1;
    if (kt2 < TT / 64 - 1) {
      stage(kt2 + 1, cur ^ 1);
      asm volatile("s_waitcnt vmcnt(8)" ::: "memory");
    } else {
      asm volatile("s_waitcnt vmcnt(0)" ::: "memory");
    }
    __builtin_amdgcn_s_barrier();

    f32x4 sacc[4];
#pragma unroll
    for (int n = 0; n < 4; ++n) sacc[n] = fz;
    __builtin_amdgcn_s_setprio(1);
#pragma unroll
    for (int kkk = 0; kkk < 4; ++kkk) {
#pragma unroll
      for (int n = 0; n < 4; ++n) {
        const int row = n * 16 + lrow;
        const int ch  = (kkk * 4 + lgrp) ^ (row & 7);
        u16x8 bfr = *(const u16x8*)((const char*)&Ks[cur][0] + row * 256 + ch * 16);
        sacc[n] = mfma16(qf[kkk], bfr, sacc[n]);
      }
    }
    __builtin_amdgcn_s_setprio(0);
#pragma unroll
    for (int n = 0; n < 4; ++n) sacc[n] *= scale;

    float rmax[4];
#pragma unroll
    for (int r = 0; r < 4; ++r)
      rmax[r] = fmaxf(fmaxf(sacc[0][r], sacc[1][r]), fmaxf(sacc[2][r], sacc[3][r]));
#pragma unroll
    for (int off = 8; off >= 1; off >>= 1)
#pragma unroll
      for (int r = 0; r < 4; ++r)
        rmax[r] = fmaxf(rmax[r], __shfl_xor(rmax[r], off, 64));

    bool need = false;
#pragma unroll
    for (int r = 0; r < 4; ++r) need = need || (rmax[r] > mst[r] + 8.0f);
    if (__any(need)) {
#pragma unroll
      for (int r = 0; r < 4; ++r) {
        float mnew  = fmaxf(mst[r], rmax[r]);
        float alpha = __expf(mst[r] - mnew);
        mst[r] = mnew;
        lst[r] *= alpha;
#pragma unroll
        for (int nf = 0; nf < 8; ++nf) oacc[nf][r] *= alpha;
      }
    }

    float rsum[4] = {0.f, 0.f, 0.f, 0.f};
#pragma unroll
    for (int n = 0; n < 4; ++n)
#pragma unroll
      for (int r = 0; r < 4; ++r) {
        float pv = __expf(sacc[n][r] - mst[r]);
        rsum[r] += pv;
        Ps[wave][lgrp * 4 + r][n * 16 + lrow] = f2bf(pv);
      }
#pragma unroll
    for (int off = 8; off >= 1; off >>= 1)
#pragma unroll
      for (int r = 0; r < 4; ++r) rsum[r] += __shfl_xor(rsum[r], off, 64);
#pragma unroll
    for (int r = 0; r < 4; ++r) lst[r] += rsum[r];

    asm volatile("s_waitcnt lgkmcnt(0)" ::: "memory");

    __builtin_amdgcn_s_setprio(1);
#pragma unroll
    for (int kk2 = 0; kk2 < 2; ++kk2) {
      u16x8 af = *(const u16x8*)&Ps[wave][lrow][kk2 * 32 + lgrp * 8];
#pragma unroll
      for (int nf = 0; nf < 8; ++nf) {
        const int vbase = nf * 2048 + kk2 * 1024 + lgrp * 256 + lrow * 8;
        u16x4 lo, hi;
        trpair(&Vs[cur][0], vbase, lo, hi);
        u16x8 bfr;
        bfr[0] = lo[0]; bfr[1] = lo[1]; bfr[2] = lo[2]; bfr[3] = lo[3];
        bfr[4] = hi[0]; bfr[5] = hi[1]; bfr[6] = hi[2]; bfr[7] = hi[3];
        oacc[nf] = mfma16(af, bfr, oacc[nf]);
      }
    }
    __builtin_amdgcn_s_setprio(0);

    __builtin_amdgcn_s_barrier();
  }

  float inv[4];
#pragma unroll
  for (int r = 0; r < 4; ++r) inv[r] = 1.0f / lst[r];
#pragma unroll
  for (int nf = 0; nf < 8; ++nf)
#pragma unroll
    for (int r = 0; r < 4; ++r)
      O[(qrow0 + lgrp * 4 + r) * os + colBase + nf * 16 + lrow] =
          f2bf(oacc[nf][r] * inv[r]);
}

// ---------------- launch ----------------------------------------------------
extern "C" void kernel_launch(void* const* d_in, const int* in_sizes, int n_in,
                              void* d_out, int out_size, void* d_ws, size_t ws_size,
                              hipStream_t stream) {
  const float* x  = (const float*)d_in[0];
  const float* fc = (const float*)d_in[1];
  const float* fs = (const float*)d_in[2];
  const float* wq = (const float*)d_in[3];
  const float* wk = (const float*)d_in[4];
  const float* wv = (const float*)d_in[5];
  const float* wo = (const float*)d_in[6];
  float* out = (float*)d_out;

  uint16_t* w16  = (uint16_t*)d_ws;
  uint16_t* xb   = w16;                   //  8,388,608  x  [4096][2048]
  uint16_t* wqkv = xb + 8388608;          // 12,582,912  [6144][2048]
  uint16_t* wob  = wqkv + 12582912;       //  4,194,304  [2048][2048]
  uint16_t* qkv  = wob + 4194304;         // 25,165,824  [4096][6144]
  uint16_t* ob   = qkv + 25165824;        //  8,388,608  [4096][2048]

  static int lds_ok = [] {
    (void)hipFuncSetAttribute((const void*)gemm256_8ph<2>,
                              hipFuncAttributeMaxDynamicSharedMemorySize, 131072);
    (void)hipFuncSetAttribute((const void*)gemm128<1>,
                              hipFuncAttributeMaxDynamicSharedMemorySize, 65536);
    return 1;
  }();
  (void)lds_ok;

  // casts
  cast_f32_bf16<<<8192, 256, 0, stream>>>(x, xb, 8388608 / 4);
  cast3_f32_bf16<<<3 * 4096, 256, 0, stream>>>(wq, wk, wv, wqkv);
  cast_f32_bf16<<<4096, 256, 0, stream>>>(wo, wob, 4194304 / 4);

  // fused QKV projection + RoPE epilogue: [4096][6144] = xb @ wqkv^T
  gemm256_8ph<2><<<(MR / 256) * (QKVS / 256), 512, 131072, stream>>>(
      xb, wqkv, qkv, fc, fs, MR, QKVS, DIM);

  // attention: Q,K,V strided views into qkv
  dim3 ga(BB * NH, TT / 64);
  attn_fwd<<<ga, 256, 0, stream>>>(qkv, qkv + DIM, qkv + 2 * DIM, ob);

  // output projection -> fp32 d_out
  gemm128<1><<<(MR / 128) * (DIM / 128), 256, 65536, stream>>>(
      ob, wob, out, nullptr, MR, DIM, DIM);
}

// Round 8
// 279.774 us; speedup vs baseline: 1.6584x; 1.0041x over previous
//
#include <hip/hip_runtime.h>
#include <stdint.h>

// Problem constants
#define BB 4
#define TT 1024
#define DIM 2048
#define NH 16
#define HD 128
#define MR 4096   // BB*TT rows
#define QKVS (3 * DIM)   // 6144: row stride of fused qkv buffer

typedef __attribute__((ext_vector_type(4))) float    f32x4;
typedef __attribute__((ext_vector_type(8))) uint16_t u16x8;
typedef __attribute__((ext_vector_type(4))) uint16_t u16x4;
typedef __attribute__((ext_vector_type(4))) short    s16x4;
typedef __attribute__((ext_vector_type(8))) __bf16   bf16x8;

static __device__ __forceinline__ uint16_t f2bf(float f) {
  uint32_t u = __builtin_bit_cast(uint32_t, f);
  u += 0x7fffu + ((u >> 16) & 1u);   // round-to-nearest-even
  return (uint16_t)(u >> 16);
}
static __device__ __forceinline__ float bf2f(uint16_t b) {
  uint32_t u = ((uint32_t)b) << 16;
  return __builtin_bit_cast(float, u);
}

static __device__ __forceinline__ f32x4 mfma16(u16x8 a, u16x8 b, f32x4 c) {
  return __builtin_amdgcn_mfma_f32_16x16x32_bf16(
      __builtin_bit_cast(bf16x8, a), __builtin_bit_cast(bf16x8, b), c, 0, 0, 0);
}

// async global->LDS, 16B per lane; LDS dest = wave-uniform base + lane*16
static __device__ __forceinline__ void load_lds_16B(const void* g, void* l) {
  __builtin_amdgcn_global_load_lds(
      (const __attribute__((address_space(1))) void*)g,
      (__attribute__((address_space(3))) void*)l, 16, 0, 0);
}

// paired hardware transpose reads at byteoff and byteoff+128.
static __device__ __forceinline__ void trpair(const uint16_t* base, int byteoff,
                                              u16x4& lo, u16x4& hi) {
  __attribute__((address_space(3))) char* ap =
      (__attribute__((address_space(3))) char*)(void*)base + byteoff;
#if defined(__has_builtin) && __has_builtin(__builtin_amdgcn_ds_read_tr16_b64_v4i16)
  s16x4 r0 = __builtin_amdgcn_ds_read_tr16_b64_v4i16(
      (__attribute__((address_space(3))) s16x4*)ap);
  s16x4 r1 = __builtin_amdgcn_ds_read_tr16_b64_v4i16(
      (__attribute__((address_space(3))) s16x4*)(ap + 128));
  lo = __builtin_bit_cast(u16x4, r0);
  hi = __builtin_bit_cast(u16x4, r1);
#else
  uint32_t a32 = (uint32_t)(uintptr_t)ap;
  asm volatile("ds_read_b64_tr_b16 %0, %2\n\t"
               "ds_read_b64_tr_b16 %1, %2 offset:128\n\t"
               "s_waitcnt lgkmcnt(0)"
               : "=&v"(lo), "=&v"(hi) : "v"(a32));
#endif
}

// ---------------- casts fp32 -> bf16 (vectorized) ----------------
__global__ __launch_bounds__(256) void cast_f32_bf16(const float* __restrict__ in,
                                                     uint16_t* __restrict__ out, int n4) {
  int i = blockIdx.x * 256 + threadIdx.x;
  if (i >= n4) return;
  f32x4 v = ((const f32x4*)in)[i];
  u16x4 o;
  o[0] = f2bf(v[0]); o[1] = f2bf(v[1]); o[2] = f2bf(v[2]); o[3] = f2bf(v[3]);
  ((u16x4*)out)[i] = o;
}

// three equal-size sources -> one contiguous dest (wq|wk|wv)
__global__ __launch_bounds__(256) void cast3_f32_bf16(const float* __restrict__ s0,
                                                      const float* __restrict__ s1,
                                                      const float* __restrict__ s2,
                                                      uint16_t* __restrict__ out) {
  const int per = 4194304 / 4;   // f32x4 chunks per matrix
  int i = blockIdx.x * 256 + threadIdx.x;          // [0, 3*per)
  const float* src = (i < per) ? s0 : (i < 2 * per) ? s1 : s2;
  int j = (i < per) ? i : (i < 2 * per) ? (i - per) : (i - 2 * per);
  f32x4 v = ((const f32x4*)src)[j];
  u16x4 o;
  o[0] = f2bf(v[0]); o[1] = f2bf(v[1]); o[2] = f2bf(v[2]); o[3] = f2bf(v[3]);
  ((u16x4*)out)[i] = o;
}

// ---------------- GEMM 256x256, BK=32, 4-slot rotation -----------------------
// C[M,N] = A[M,K] * Bt[N,K]^T (bf16 row-major). 512 thr = 8 waves (2M x 4N);
// per-wave C = 128x64 = 8x4 16x16 frags -> 12 ds_read_b128 / 32 MFMA per tile
// (0.375 reads/MFMA, m201 ratio). LDS: 4 slots x (A 16KB + B 16KB) = 128 KiB.
// gemm128-proven counted-vmcnt rotation: stage T+3 after the per-tile barrier;
// steady-state wait vmcnt(8) (T+1,T+2 stay in flight; lead = 3 tiles); vmcnt
// drains only in the 2-tile epilogue. Swizzle ch^((row>>1)&3) on 16B chunks
// (4/row), applied on global source (linear gload_lds dest) and ds_read addr.
// MODE: 1 = f32 out, 2 = bf16 out + fused RoPE on cols [0, 2*DIM).
template <int MODE>
__global__ __launch_bounds__(512, 1) void gemm256q(const uint16_t* __restrict__ A,
                                                   const uint16_t* __restrict__ Bt,
                                                   float* __restrict__ Cf,
                                                   uint16_t* __restrict__ Cb,
                                                   const float* __restrict__ cosT,
                                                   const float* __restrict__ sinT,
                                                   int M, int N, int K) {
  extern __shared__ __attribute__((aligned(16))) uint16_t smem[];  // 131072 B
  const int tid  = threadIdx.x;
  const int lane = tid & 63;
  const int wave = tid >> 6;          // 0..7
  const int lrow = lane & 15;
  const int lgrp = lane >> 4;
  const int wr   = (wave >> 2) * 128; // 0 / 128
  const int wc   = (wave & 3) * 64;   // 0,64,128,192

  // T1: XCD-aware block swizzle (grid % 8 == 0)
  const int nbx = N >> 8, nby = M >> 8;
  const int nwg = nbx * nby;
  const int wg  = ((int)blockIdx.x & 7) * (nwg >> 3) + ((int)blockIdx.x >> 3);
  const long bRow = (long)(wg / nbx) << 8;
  const long bCol = (long)(wg % nbx) << 8;

  const f32x4 fz = {0.f, 0.f, 0.f, 0.f};
  f32x4 acc[8][4];
#pragma unroll
  for (int m = 0; m < 8; ++m)
#pragma unroll
    for (int n = 0; n < 4; ++n) acc[m][n] = fz;

  // stage one K-tile (A 16KB + B 16KB) into slot: 4 loads per thread.
  // LDS[row][c'] = G[row][c' ^ ((row>>1)&3)], 16B chunks, 4/row (64B rows).
  auto stage = [&](int kt, int slot) {
    const long kb = (long)kt << 5;
    char* Abase = (char*)smem + slot * 32768;
    char* Bbase = Abase + 16384;
#pragma unroll
    for (int i = 0; i < 2; ++i) {
      const int L   = (i * 512 + tid) * 16;
      const int row = L >> 6;                           // 0..255
      const int c   = ((L >> 4) & 3) ^ ((row >> 1) & 3);
      load_lds_16B(A + (bRow + row) * (long)K + kb + c * 8, Abase + L);
    }
#pragma unroll
    for (int i = 0; i < 2; ++i) {
      const int L   = (i * 512 + tid) * 16;
      const int row = L >> 6;
      const int c   = ((L >> 4) & 3) ^ ((row >> 1) & 3);
      load_lds_16B(Bt + (bCol + row) * (long)K + kb + c * 8, Bbase + L);
    }
  };

  const int NT = K >> 5;   // 64 K-tiles
  stage(0, 0); stage(1, 1); stage(2, 2);   // 12 loads in flight

  for (int t = 0; t < NT; ++t) {
    const int cur = t & 3;
    if (t < NT - 2)       asm volatile("s_waitcnt vmcnt(8)" ::: "memory");
    else if (t == NT - 2) asm volatile("s_waitcnt vmcnt(4)" ::: "memory");
    else                  asm volatile("s_waitcnt vmcnt(0)" ::: "memory");
    __builtin_amdgcn_s_barrier();          // tile t landed; slot (t-1)&3 free
    if (t + 3 < NT) stage(t + 3, (t + 3) & 3);

    const char* Ab = (const char*)smem + cur * 32768;
    const char* Bb = Ab + 16384;
    u16x8 af[8], bf[4];
#pragma unroll
    for (int m = 0; m < 8; ++m) {
      const int row = wr + m * 16 + lrow;
      af[m] = *(const u16x8*)(Ab + row * 64 + (lgrp ^ ((row >> 1) & 3)) * 16);
    }
#pragma unroll
    for (int n = 0; n < 4; ++n) {
      const int row = wc + n * 16 + lrow;
      bf[n] = *(const u16x8*)(Bb + row * 64 + (lgrp ^ ((row >> 1) & 3)) * 16);
    }
    __builtin_amdgcn_s_setprio(1);
#pragma unroll
    for (int m = 0; m < 8; ++m)
#pragma unroll
      for (int n = 0; n < 4; ++n) acc[m][n] = mfma16(af[m], bf[n], acc[m][n]);
    __builtin_amdgcn_s_setprio(0);
  }

  // epilogue (MODE 2: fused RoPE on q/k column range)
  const bool doRope = (MODE == 2) && (bCol < 2 * DIM);
#pragma unroll
  for (int m = 0; m < 8; ++m)
#pragma unroll
    for (int n = 0; n < 4; ++n) {
      const long grow0 = bRow + wr + m * 16 + lgrp * 4;
      const long gcol  = bCol + wc + n * 16 + lrow;
      if (doRope) {
        const int  fi  = ((int)gcol >> 1) & 63;
        const bool odd = (gcol & 1) != 0;
#pragma unroll
        for (int r = 0; r < 4; ++r) {
          const long grow = grow0 + r;
          const int  ttt  = (int)grow & (TT - 1);
          float v = acc[m][n][r];
          float p = __shfl_xor(v, 1, 64);   // partner column (lane^1)
          float cc = cosT[ttt * 64 + fi];
          float ss = sinT[ttt * 64 + fi];
          float o  = odd ? (p * ss + v * cc) : (v * cc - p * ss);
          Cb[grow * (long)N + gcol] = f2bf(o);
        }
      } else {
#pragma unroll
        for (int r = 0; r < 4; ++r) {
          const long idx = (grow0 + r) * (long)N + gcol;
          if (MODE == 1) Cf[idx] = acc[m][n][r];
          else           Cb[idx] = f2bf(acc[m][n][r]);
        }
      }
    }
}

// ---------------- GEMM 128x128, BK=32, quad-buffered (out-proj) --------------
template <int MODE>   // 1 = f32 out
__global__ __launch_bounds__(256, 2) void gemm128(const uint16_t* __restrict__ A,
                                                  const uint16_t* __restrict__ Bt,
                                                  float* __restrict__ Cf,
                                                  uint16_t* __restrict__ Cb,
                                                  int M, int N, int K) {
  extern __shared__ __attribute__((aligned(16))) uint16_t smem[];  // 65536 B
  const int tid  = threadIdx.x;
  const int lane = tid & 63;
  const int wave = tid >> 6;
  const int lrow = lane & 15;
  const int lgrp = lane >> 4;
  const int wr   = (wave >> 1) * 64;
  const int wc   = (wave & 1) * 64;

  const int nbx = N >> 7, nby = M >> 7;
  const int nwg = nbx * nby;
  const int wg  = ((int)blockIdx.x & 7) * (nwg >> 3) + ((int)blockIdx.x >> 3);
  const long bRow = (long)(wg / nbx) << 7;
  const long bCol = (long)(wg % nbx) << 7;

  const f32x4 fz = {0.f, 0.f, 0.f, 0.f};
  f32x4 acc[4][4];
#pragma unroll
  for (int m = 0; m < 4; ++m)
#pragma unroll
    for (int n = 0; n < 4; ++n) acc[m][n] = fz;

  auto stage = [&](int kt, int buf) {
    const long kb = (long)kt << 5;
    char* base = (char*)smem + buf * 16384;
#pragma unroll
    for (int i = 0; i < 2; ++i) {
      const int L   = (i * 256 + tid) * 16;
      const int row = L >> 6;
      const int c   = ((L >> 4) & 3) ^ ((row >> 1) & 3);
      load_lds_16B(A + (bRow + row) * (long)K + kb + c * 8, base + L);
    }
#pragma unroll
    for (int i = 0; i < 2; ++i) {
      const int L   = (i * 256 + tid) * 16;
      const int row = L >> 6;
      const int c   = ((L >> 4) & 3) ^ ((row >> 1) & 3);
      load_lds_16B(Bt + (bCol + row) * (long)K + kb + c * 8, base + 8192 + L);
    }
  };

  const int NT = K >> 5;
  stage(0, 0); stage(1, 1); stage(2, 2);

  for (int t = 0; t < NT; ++t) {
    const int cur = t & 3;
    if (t < NT - 2)       asm volatile("s_waitcnt vmcnt(8)" ::: "memory");
    else if (t == NT - 2) asm volatile("s_waitcnt vmcnt(4)" ::: "memory");
    else                  asm volatile("s_waitcnt vmcnt(0)" ::: "memory");
    __builtin_amdgcn_s_barrier();
    if (t + 3 < NT) stage(t + 3, (t + 3) & 3);

    const char* Ab = (const char*)smem + cur * 16384;
    const char* Bb = Ab + 8192;
    u16x8 af[4], bf[4];
#pragma unroll
    for (int m = 0; m < 4; ++m) {
      const int row = wr + m * 16 + lrow;
      af[m] = *(const u16x8*)(Ab + row * 64 + (lgrp ^ ((row >> 1) & 3)) * 16);
    }
#pragma unroll
    for (int n = 0; n < 4; ++n) {
      const int row = wc + n * 16 + lrow;
      bf[n] = *(const u16x8*)(Bb + row * 64 + (lgrp ^ ((row >> 1) & 3)) * 16);
    }
    __builtin_amdgcn_s_setprio(1);
#pragma unroll
    for (int m = 0; m < 4; ++m)
#pragma unroll
      for (int n = 0; n < 4; ++n) acc[m][n] = mfma16(af[m], bf[n], acc[m][n]);
    __builtin_amdgcn_s_setprio(0);
  }

#pragma unroll
  for (int m = 0; m < 4; ++m)
#pragma unroll
    for (int n = 0; n < 4; ++n) {
      const long grow0 = bRow + wr + m * 16 + lgrp * 4;
      const long gcol  = bCol + wc + n * 16 + lrow;
#pragma unroll
      for (int r = 0; r < 4; ++r) {
        const long idx = (grow0 + r) * (long)N + gcol;
        if (MODE == 1) Cf[idx] = acc[m][n][r];
        else           Cb[idx] = f2bf(acc[m][n][r]);
      }
    }
}

// ---------------- Flash attention fwd ---------------------------------------
__global__ __launch_bounds__(256) void attn_fwd(const uint16_t* __restrict__ Q,
                                                const uint16_t* __restrict__ K,
                                                const uint16_t* __restrict__ V,
                                                uint16_t* __restrict__ O) {
  __shared__ __attribute__((aligned(16))) uint16_t Ks[2][64 * 128];
  __shared__ __attribute__((aligned(16))) uint16_t Vs[2][64 * 128];
  __shared__ __attribute__((aligned(16))) uint16_t Ps[4][16][72];
  const int tid  = threadIdx.x;
  const int lane = tid & 63;
  const int wave = tid >> 6;
  const int lrow = lane & 15;
  const int lgrp = lane >> 4;
  const int b  = blockIdx.x >> 4;
  const int h  = blockIdx.x & 15;
  const int qt = blockIdx.y;
  const long colBase = (long)h * HD;
  const long rs = QKVS;
  const long os = DIM;
  const long qrow0 = (long)b * TT + qt * 64 + wave * 16;

  u16x8 qf[4];
#pragma unroll
  for (int kkk = 0; kkk < 4; ++kkk)
    qf[kkk] = *(const u16x8*)(Q + (qrow0 + lrow) * rs + colBase + kkk * 32 + lgrp * 8);

  const f32x4 fz = {0.f, 0.f, 0.f, 0.f};
  f32x4 oacc[8];
#pragma unroll
  for (int nf = 0; nf < 8; ++nf) oacc[nf] = fz;
  float mst[4] = {-1e30f, -1e30f, -1e30f, -1e30f};
  float lst[4] = {0.f, 0.f, 0.f, 0.f};
  const float scale = 0.08838834764831845f;

  auto stage = [&](int kt, int buf) {
    const long krow = (long)b * TT + kt * 64;
#pragma unroll
    for (int i = 0; i < 4; ++i) {
      const int L = (i * 256 + tid) * 16;
      const int krw = L >> 8;
      const int ksc = ((L >> 4) & 15) ^ (krw & 7);
      load_lds_16B(K + (krow + krw) * rs + colBase + ksc * 8,
                   (char*)&Ks[buf][0] + L);
      const int vbl = L >> 11;
      const int vkv = ((L >> 7) & 15) * 4 + ((L >> 5) & 3);
      const int vd  = vbl * 16 + ((L >> 4) & 1) * 8;
      load_lds_16B(V + (krow + vkv) * rs + colBase + vd,
                   (char*)&Vs[buf][0] + L);
    }
  };

  stage(0, 0);

  for (int kt2 = 0; kt2 < TT / 64; ++kt2) {
    const int cur = kt2 & 1;
    if (kt2 < TT / 64 - 1) {
      stage(kt2 + 1, cur ^ 1);
      asm volatile("s_waitcnt vmcnt(8)" ::: "memory");
    } else {
      asm volatile("s_waitcnt vmcnt(0)" ::: "memory");
    }
    __builtin_amdgcn_s_barrier();

    f32x4 sacc[4];
#pragma unroll
    for (int n = 0; n < 4; ++n) sacc[n] = fz;
    __builtin_amdgcn_s_setprio(1);
#pragma unroll
    for (int kkk = 0; kkk < 4; ++kkk) {
#pragma unroll
      for (int n = 0; n < 4; ++n) {
        const int row = n * 16 + lrow;
        const int ch  = (kkk * 4 + lgrp) ^ (row & 7);
        u16x8 bfr = *(const u16x8*)((const char*)&Ks[cur][0] + row * 256 + ch * 16);
        sacc[n] = mfma16(qf[kkk], bfr, sacc[n]);
      }
    }
    __builtin_amdgcn_s_setprio(0);
#pragma unroll
    for (int n = 0; n < 4; ++n) sacc[n] *= scale;

    float rmax[4];
#pragma unroll
    for (int r = 0; r < 4; ++r)
      rmax[r] = fmaxf(fmaxf(sacc[0][r], sacc[1][r]), fmaxf(sacc[2][r], sacc[3][r]));
#pragma unroll
    for (int off = 8; off >= 1; off >>= 1)
#pragma unroll
      for (int r = 0; r < 4; ++r)
        rmax[r] = fmaxf(rmax[r], __shfl_xor(rmax[r], off, 64));

    bool need = false;
#pragma unroll
    for (int r = 0; r < 4; ++r) need = need || (rmax[r] > mst[r] + 8.0f);
    if (__any(need)) {
#pragma unroll
      for (int r = 0; r < 4; ++r) {
        float mnew  = fmaxf(mst[r], rmax[r]);
        float alpha = __expf(mst[r] - mnew);
        mst[r] = mnew;
        lst[r] *= alpha;
#pragma unroll
        for (int nf = 0; nf < 8; ++nf) oacc[nf][r] *= alpha;
      }
    }

    float rsum[4] = {0.f, 0.f, 0.f, 0.f};
#pragma unroll
    for (int n = 0; n < 4; ++n)
#pragma unroll
      for (int r = 0; r < 4; ++r) {
        float pv = __expf(sacc[n][r] - mst[r]);
        rsum[r] += pv;
        Ps[wave][lgrp * 4 + r][n * 16 + lrow] = f2bf(pv);
      }
#pragma unroll
    for (int off = 8; off >= 1; off >>= 1)
#pragma unroll
      for (int r = 0; r < 4; ++r) rsum[r] += __shfl_xor(rsum[r], off, 64);
#pragma unroll
    for (int r = 0; r < 4; ++r) lst[r] += rsum[r];

    asm volatile("s_waitcnt lgkmcnt(0)" ::: "memory");

    __builtin_amdgcn_s_setprio(1);
#pragma unroll
    for (int kk2 = 0; kk2 < 2; ++kk2) {
      u16x8 af = *(const u16x8*)&Ps[wave][lrow][kk2 * 32 + lgrp * 8];
#pragma unroll
      for (int nf = 0; nf < 8; ++nf) {
        const int vbase = nf * 2048 + kk2 * 1024 + lgrp * 256 + lrow * 8;
        u16x4 lo, hi;
        trpair(&Vs[cur][0], vbase, lo, hi);
        u16x8 bfr;
        bfr[0] = lo[0]; bfr[1] = lo[1]; bfr[2] = lo[2]; bfr[3] = lo[3];
        bfr[4] = hi[0]; bfr[5] = hi[1]; bfr[6] = hi[2]; bfr[7] = hi[3];
        oacc[nf] = mfma16(af, bfr, oacc[nf]);
      }
    }
    __builtin_amdgcn_s_setprio(0);

    __builtin_amdgcn_s_barrier();
  }

  float inv[4];
#pragma unroll
  for (int r = 0; r < 4; ++r) inv[r] = 1.0f / lst[r];
#pragma unroll
  for (int nf = 0; nf < 8; ++nf)
#pragma unroll
    for (int r = 0; r < 4; ++r)
      O[(qrow0 + lgrp * 4 + r) * os + colBase + nf * 16 + lrow] =
          f2bf(oacc[nf][r] * inv[r]);
}

// ---------------- launch ----------------------------------------------------
extern "C" void kernel_launch(void* const* d_in, const int* in_sizes, int n_in,
                              void* d_out, int out_size, void* d_ws, size_t ws_size,
                              hipStream_t stream) {
  const float* x  = (const float*)d_in[0];
  const float* fc = (const float*)d_in[1];
  const float* fs = (const float*)d_in[2];
  const float* wq = (const float*)d_in[3];
  const float* wk = (const float*)d_in[4];
  const float* wv = (const float*)d_in[5];
  const float* wo = (const float*)d_in[6];
  float* out = (float*)d_out;

  uint16_t* w16  = (uint16_t*)d_ws;
  uint16_t* xb   = w16;                   //  8,388,608  x  [4096][2048]
  uint16_t* wqkv = xb + 8388608;          // 12,582,912  [6144][2048]
  uint16_t* wob  = wqkv + 12582912;       //  4,194,304  [2048][2048]
  uint16_t* qkv  = wob + 4194304;         // 25,165,824  [4096][6144]
  uint16_t* ob   = qkv + 25165824;        //  8,388,608  [4096][2048]

  static int lds_ok = [] {
    (void)hipFuncSetAttribute((const void*)gemm256q<2>,
                              hipFuncAttributeMaxDynamicSharedMemorySize, 131072);
    (void)hipFuncSetAttribute((const void*)gemm128<1>,
                              hipFuncAttributeMaxDynamicSharedMemorySize, 65536);
    return 1;
  }();
  (void)lds_ok;

  // casts
  cast_f32_bf16<<<8192, 256, 0, stream>>>(x, xb, 8388608 / 4);
  cast3_f32_bf16<<<3 * 4096, 256, 0, stream>>>(wq, wk, wv, wqkv);
  cast_f32_bf16<<<4096, 256, 0, stream>>>(wo, wob, 4194304 / 4);

  // fused QKV projection + RoPE epilogue: [4096][6144] = xb @ wqkv^T
  gemm256q<2><<<(MR / 256) * (QKVS / 256), 512, 131072, stream>>>(
      xb, wqkv, nullptr, qkv, fc, fs, MR, QKVS, DIM);

  // attention: Q,K,V strided views into qkv
  dim3 ga(BB * NH, TT / 64);
  attn_fwd<<<ga, 256, 0, stream>>>(qkv, qkv + DIM, qkv + 2 * DIM, ob);

  // output projection -> fp32 d_out
  gemm128<1><<<(MR / 128) * (DIM / 128), 256, 65536, stream>>>(
      ob, wob, out, nullptr, MR, DIM, DIM);
}